// Round 1
// baseline (4401.567 us; speedup 1.0000x reference)
//
#include <hip/hip_runtime.h>
#include <cstdio>
#include <cstddef>

// Problem dims
#define BB    256
#define TT    24
#define NFEAT 12
#define DIM   256
#define NH    8
#define DKH   32
#define FFD   512
#define SEQ_T 128
#define SEQ_F 153
#define NLAY  2

// ---------------------------------------------------------------------------
// PE table: pe[s,i] = sin/cos(s / 10000^(2*(i/2)/D))
__global__ void pe_kernel(float* __restrict__ pe) {
    int s = blockIdx.x;      // 0..152
    int i = threadIdx.x;     // 0..255
    float e = (float)(2 * (i / 2)) * (1.0f / 256.0f);
    float freq = expf(-e * 9.210340371976184f); // ln(10000)
    float ang = (float)s * freq;
    pe[s * 256 + i] = (i & 1) ? cosf(ang) : sinf(ang);
}

// Transpose gru_Whh (768x256) -> (256x768) for coalesced reads in scan
__global__ void transpose_whh_kernel(const float* __restrict__ Whh, float* __restrict__ Wt) {
    int n = blockIdx.x;   // 0..767
    int k = threadIdx.x;  // 0..255
    Wt[(size_t)k * 768 + n] = Whh[(size_t)n * 256 + k];
}

// ---------------------------------------------------------------------------
// GRU-D scan: one block (256 threads) per batch element, 24 sequential steps.
__global__ __launch_bounds__(256) void grud_kernel(
    const float* __restrict__ x, const float* __restrict__ h0,
    const float* __restrict__ m, const float* __restrict__ dd,
    const float* __restrict__ x_m,
    const float* __restrict__ dec_w, const float* __restrict__ dec_b,
    const float* __restrict__ hd_W, const float* __restrict__ hd_b,
    const float* __restrict__ Wih, const float* __restrict__ bih,
    const float* __restrict__ WhhT, const float* __restrict__ bhh,
    float* __restrict__ emb)
{
    int b = blockIdx.x;
    int j = threadIdx.x; // 0..255
    __shared__ float hcs[256];
    __shared__ float hdecs[256];
    __shared__ float dts[12];
    __shared__ float xcm[24];

    float hdw[12];
#pragma unroll
    for (int i = 0; i < 12; i++) hdw[i] = hd_W[j * 12 + i];
    float wr[24], wz[24], wn[24];
#pragma unroll
    for (int i = 0; i < 24; i++) {
        wr[i] = Wih[(size_t)j * 24 + i];
        wz[i] = Wih[(size_t)(j + 256) * 24 + i];
        wn[i] = Wih[(size_t)(j + 512) * 24 + i];
    }
    float bihr = bih[j], bihz = bih[j + 256], bihn = bih[j + 512];
    float bhhr = bhh[j], bhhz = bhh[j + 256], bhhn = bhh[j + 512];
    float hdb = hd_b[j];

    hcs[j] = h0[(size_t)b * 256 + j];
    __syncthreads();

    for (int t = 0; t < TT; t++) {
        if (j < 12) {
            size_t idx = ((size_t)b * TT + t) * NFEAT + j;
            float dv = dd[idx];
            float xv = x[idx];
            float mv = m[idx];
            float xd = expf(-fmaxf(dv * dec_w[j] + dec_b[j], 0.0f));
            dts[j] = dv;
            xcm[j] = mv * xv + (1.0f - mv) * xd * xv + (1.0f - mv) * (1.0f - xd) * x_m[j];
            xcm[12 + j] = mv;
        }
        __syncthreads();
        // h decay
        float acc = hdb;
#pragma unroll
        for (int i = 0; i < 12; i++) acc += hdw[i] * dts[i];
        float hdec = expf(-fmaxf(acc, 0.0f)) * hcs[j];
        hdecs[j] = hdec;
        __syncthreads();
        // input gates
        float gr = bihr, gz = bihz, gn = bihn;
#pragma unroll
        for (int i = 0; i < 24; i++) {
            float xi = xcm[i];
            gr += wr[i] * xi; gz += wz[i] * xi; gn += wn[i] * xi;
        }
        // hidden gates (coalesced WhhT reads, broadcast hdecs)
        float hr = bhhr, hz = bhhz, hn = bhhn;
        for (int k = 0; k < 256; k++) {
            float hk = hdecs[k];
            const float* wrow = WhhT + (size_t)k * 768;
            hr += wrow[j] * hk;
            hz += wrow[256 + j] * hk;
            hn += wrow[512 + j] * hk;
        }
        float r = 1.0f / (1.0f + expf(-(gr + hr)));
        float z = 1.0f / (1.0f + expf(-(gz + hz)));
        float n = tanhf(gn + r * hn);
        float hnew = (1.0f - z) * n + z * hdec;
        hcs[j] = hnew;
        emb[((size_t)b * TT + t) * 256 + j] = hnew;
        __syncthreads();
    }
}

// ---------------------------------------------------------------------------
// Embedding gather: out[r,:] = txt_emb[txts[r],:]
__global__ void gather_kernel(const int* __restrict__ txts, const float* __restrict__ txt_emb,
                              float* __restrict__ outp) {
    int r = blockIdx.x;
    int i = threadIdx.x;
    outp[(size_t)r * 256 + i] = txt_emb[(size_t)txts[r] * 256 + i];
}

// Build fusion sequence: [cls, emb(24), txt_out(128)]
__global__ void build_seq_kernel(const float* __restrict__ emb, const float* __restrict__ encT,
                                 const float* __restrict__ fcls, float* __restrict__ seq) {
    int r = blockIdx.x;
    int i = threadIdx.x;
    int b = r / SEQ_F, s = r - b * SEQ_F;
    float v;
    if (s == 0)       v = fcls[i];
    else if (s < 25)  v = emb[((size_t)b * TT + (s - 1)) * 256 + i];
    else              v = encT[((size_t)b * SEQ_T + (s - 25)) * 256 + i];
    seq[(size_t)r * 256 + i] = v;
}

// ---------------------------------------------------------------------------
// Tiled fp32 GEMM: C(M,N) = A(M,K) @ W(N,K)^T + bias, optional ReLU.
// M,N multiples of 64; K multiple of 16.
template <int RELU>
__global__ __launch_bounds__(256) void gemm_nt_kernel(
    const float* __restrict__ A, const float* __restrict__ W,
    const float* __restrict__ bias, float* __restrict__ C,
    int M, int N, int K)
{
    __shared__ float As[16][65];
    __shared__ float Bs[16][65];
    const int bm = blockIdx.y * 64, bn = blockIdx.x * 64;
    const int tid = threadIdx.x;
    const int lr = tid >> 2;          // 0..63
    const int lk = (tid & 3) << 2;    // 0,4,8,12
    const int tx = tid & 15, ty = tid >> 4;
    float acc[4][4] = {};
    for (int k0 = 0; k0 < K; k0 += 16) {
        float4 a = *reinterpret_cast<const float4*>(A + (size_t)(bm + lr) * K + k0 + lk);
        float4 w = *reinterpret_cast<const float4*>(W + (size_t)(bn + lr) * K + k0 + lk);
        As[lk + 0][lr] = a.x; As[lk + 1][lr] = a.y; As[lk + 2][lr] = a.z; As[lk + 3][lr] = a.w;
        Bs[lk + 0][lr] = w.x; Bs[lk + 1][lr] = w.y; Bs[lk + 2][lr] = w.z; Bs[lk + 3][lr] = w.w;
        __syncthreads();
#pragma unroll
        for (int k = 0; k < 16; k++) {
            float av[4], bv[4];
#pragma unroll
            for (int i = 0; i < 4; i++) av[i] = As[k][ty * 4 + i];
#pragma unroll
            for (int jj = 0; jj < 4; jj++) bv[jj] = Bs[k][tx + 16 * jj];
#pragma unroll
            for (int i = 0; i < 4; i++)
#pragma unroll
                for (int jj = 0; jj < 4; jj++) acc[i][jj] += av[i] * bv[jj];
        }
        __syncthreads();
    }
#pragma unroll
    for (int i = 0; i < 4; i++) {
        int row = bm + ty * 4 + i;
#pragma unroll
        for (int jj = 0; jj < 4; jj++) {
            int col = bn + tx + 16 * jj;
            float v = acc[i][jj] + bias[col];
            if (RELU) v = fmaxf(v, 0.0f);
            C[(size_t)row * N + col] = v;
        }
    }
}

// ---------------------------------------------------------------------------
// LayerNorm(row) * g + b + PE[s]   (input projection epilogue)
__global__ __launch_bounds__(64) void ln_pe_kernel(
    const float* __restrict__ y, const float* __restrict__ g, const float* __restrict__ b,
    const float* __restrict__ pe, float* __restrict__ outp, int S)
{
    int r = blockIdx.x, t = threadIdx.x;
    const float* yr = y + (size_t)r * 256;
    float v[4];
    float s = 0.0f;
#pragma unroll
    for (int i = 0; i < 4; i++) { v[i] = yr[t + 64 * i]; s += v[i]; }
#pragma unroll
    for (int o = 32; o >= 1; o >>= 1) s += __shfl_xor(s, o, 64);
    float mean = s * (1.0f / 256.0f);
    float vs = 0.0f;
#pragma unroll
    for (int i = 0; i < 4; i++) { float dlt = v[i] - mean; vs += dlt * dlt; }
#pragma unroll
    for (int o = 32; o >= 1; o >>= 1) vs += __shfl_xor(vs, o, 64);
    float rstd = rsqrtf(vs * (1.0f / 256.0f) + 1e-5f);
    int srow = r % S;
#pragma unroll
    for (int i = 0; i < 4; i++) {
        int c = t + 64 * i;
        outp[(size_t)r * 256 + c] = (v[i] - mean) * rstd * g[c] + b[c] + pe[srow * 256 + c];
    }
}

// LayerNorm(y + res) * g + b, then *npad mask. out may alias res.
__global__ __launch_bounds__(64) void add_ln_mask_kernel(
    const float* __restrict__ y, const float* __restrict__ res,
    const float* __restrict__ g, const float* __restrict__ b,
    const int* __restrict__ lengths, int len_add, int S, float* __restrict__ outp)
{
    int r = blockIdx.x, t = threadIdx.x;
    int bb = r / S, srow = r - bb * S;
    float mask = (srow < lengths[bb] + len_add) ? 1.0f : 0.0f;
    float v[4];
    float s = 0.0f;
#pragma unroll
    for (int i = 0; i < 4; i++) {
        v[i] = y[(size_t)r * 256 + t + 64 * i] + res[(size_t)r * 256 + t + 64 * i];
        s += v[i];
    }
#pragma unroll
    for (int o = 32; o >= 1; o >>= 1) s += __shfl_xor(s, o, 64);
    float mean = s * (1.0f / 256.0f);
    float vs = 0.0f;
#pragma unroll
    for (int i = 0; i < 4; i++) { float dlt = v[i] - mean; vs += dlt * dlt; }
#pragma unroll
    for (int o = 32; o >= 1; o >>= 1) vs += __shfl_xor(vs, o, 64);
    float rstd = rsqrtf(vs * (1.0f / 256.0f) + 1e-5f);
#pragma unroll
    for (int i = 0; i < 4; i++) {
        int c = t + 64 * i;
        outp[(size_t)r * 256 + c] = ((v[i] - mean) * rstd * g[c] + b[c]) * mask;
    }
}

// ---------------------------------------------------------------------------
// Fused attention: one block per (b,h). K/V staged in LDS; one query row per
// thread; two-pass softmax over k < len; masked keys skipped entirely.
__global__ __launch_bounds__(192) void attn_kernel(
    const float* __restrict__ qkv, float* __restrict__ ctx,
    const int* __restrict__ lengths, int len_add, int S)
{
    __shared__ float Ks[SEQ_F][32];
    __shared__ float Vs[SEQ_F][32];
    int bh = blockIdx.x;
    int b = bh >> 3, h = bh & 7;
    int tid = threadIdx.x;
    int len = lengths[b] + len_add;
    for (int idx = tid; idx < S * 32; idx += 192) {
        int s = idx >> 5, dd2 = idx & 31;
        size_t base = ((size_t)(b * S + s)) * 768 + h * 32 + dd2;
        Ks[s][dd2] = qkv[base + 256];
        Vs[s][dd2] = qkv[base + 512];
    }
    __syncthreads();
    if (tid < S) {
        float q[32];
        size_t qb = ((size_t)(b * S + tid)) * 768 + h * 32;
#pragma unroll
        for (int d2 = 0; d2 < 32; d2++) q[d2] = qkv[qb + d2] * 0.17677669529663687f; // 1/sqrt(32)
        float mmax = -1e30f;
        for (int k2 = 0; k2 < len; k2++) {
            float sc = 0.0f;
#pragma unroll
            for (int d2 = 0; d2 < 32; d2++) sc += q[d2] * Ks[k2][d2];
            mmax = fmaxf(mmax, sc);
        }
        float l = 0.0f;
        float cacc[32] = {};
        for (int k2 = 0; k2 < len; k2++) {
            float sc = 0.0f;
#pragma unroll
            for (int d2 = 0; d2 < 32; d2++) sc += q[d2] * Ks[k2][d2];
            float p = expf(sc - mmax);
            l += p;
#pragma unroll
            for (int d2 = 0; d2 < 32; d2++) cacc[d2] += p * Vs[k2][d2];
        }
        float inv = 1.0f / l;
        size_t ob = ((size_t)(b * S + tid)) * 256 + h * 32;
#pragma unroll
        for (int d2 = 0; d2 < 32; d2++) ctx[ob + d2] = cacc[d2] * inv;
    }
}

// ---------------------------------------------------------------------------
// Classifier: h1[k,b,h]=relu((ci@fc1_W[k,h]+b)/sqrt(1+eps)*g+b); out=sigmoid(h1@fc2+b2)
__global__ __launch_bounds__(64) void classifier_kernel(
    const float* __restrict__ encF, const float* __restrict__ age, const float* __restrict__ gen,
    const float* __restrict__ fc1_W, const float* __restrict__ fc1_b,
    const float* __restrict__ bn_g, const float* __restrict__ bn_b,
    const float* __restrict__ fc2_W, const float* __restrict__ fc2_b,
    float* __restrict__ outp)
{
    int k = blockIdx.x;  // 0..11
    int b = blockIdx.y;  // 0..255
    int t = threadIdx.x; // 0..63
    const float* cls = encF + (size_t)b * SEQ_F * 256; // row s=0
    const float* wrow = fc1_W + ((size_t)k * 64 + t) * 258;
    float acc = fc1_b[k * 64 + t];
    for (int d2 = 0; d2 < 256; d2++) acc += cls[d2] * wrow[d2];
    acc += age[b] * wrow[256] + gen[b] * wrow[257];
    const float RSQ = 0.99999500003749980e0f; // 1/sqrt(1+1e-5)
    acc = acc * RSQ * bn_g[k * 64 + t] + bn_b[k * 64 + t];
    acc = fmaxf(acc, 0.0f);
    float p = acc * fc2_W[k * 64 + t];
#pragma unroll
    for (int o = 32; o >= 1; o >>= 1) p += __shfl_xor(p, o, 64);
    if (t == 0) outp[k * 256 + b] = 1.0f / (1.0f + expf(-(p + fc2_b[k])));
}

// ---------------------------------------------------------------------------
// Host-side encoder driver (enqueue only)
static void run_encoder(float* enc, float* actx /* A-staging + ctx region */, float* scr,
                        const float* pe, int S,
                        const float* in_W, const float* in_b,
                        const float* attn_W, const float* attn_b,
                        const float* ff_W1, const float* ff_b1,
                        const float* ff_W2, const float* ff_b2,
                        const float* ln_g, const float* ln_b,
                        const int* lengths, int len_add, hipStream_t stream)
{
    int M = BB * S;
    // input projection: scr = A @ in_W^T + in_b; enc = LN(scr)*g0+b0 + PE
    gemm_nt_kernel<0><<<dim3(256 / 64, M / 64), 256, 0, stream>>>(actx, in_W, in_b, scr, M, 256, 256);
    ln_pe_kernel<<<M, 64, 0, stream>>>(scr, ln_g, ln_b, pe, enc, S);
    for (int l = 0; l < NLAY; l++) {
        const float* Wqkv = attn_W + (size_t)l * 4 * 65536;       // q,k,v rows contiguous
        const float* bqkv = attn_b + (size_t)l * 4 * 256;
        const float* Wout = attn_W + ((size_t)l * 4 + 3) * 65536;
        const float* bout = attn_b + ((size_t)l * 4 + 3) * 256;
        // qkv = enc @ Wqkv^T (N=768)
        gemm_nt_kernel<0><<<dim3(768 / 64, M / 64), 256, 0, stream>>>(enc, Wqkv, bqkv, scr, M, 768, 256);
        // attention -> ctx
        attn_kernel<<<BB * NH, 192, 0, stream>>>(scr, actx, lengths, len_add, S);
        // out proj: y = ctx @ Wout^T + bout   (scr reused: qkv dead)
        gemm_nt_kernel<0><<<dim3(256 / 64, M / 64), 256, 0, stream>>>(actx, Wout, bout, scr, M, 256, 256);
        // enc = LN(y + enc)*g+b * npad
        add_ln_mask_kernel<<<M, 64, 0, stream>>>(scr, enc, ln_g + (1 + 2 * l) * 256, ln_b + (1 + 2 * l) * 256,
                                                 lengths, len_add, S, enc);
        // ff1: y1 = relu(enc @ W1^T + b1)  (M x 512) in scr
        gemm_nt_kernel<1><<<dim3(512 / 64, M / 64), 256, 0, stream>>>(enc, ff_W1 + (size_t)l * 512 * 256,
                                                                      ff_b1 + l * 512, scr, M, 512, 256);
        // ff2: y2 = y1 @ W2^T + b2  (M x 256) in actx (ctx dead)
        gemm_nt_kernel<0><<<dim3(256 / 64, M / 64), 256, 0, stream>>>(scr, ff_W2 + (size_t)l * 256 * 512,
                                                                      ff_b2 + l * 256, actx, M, 256, 512);
        // enc = LN(y2 + enc)*g+b * npad
        add_ln_mask_kernel<<<M, 64, 0, stream>>>(actx, enc, ln_g + (2 + 2 * l) * 256, ln_b + (2 + 2 * l) * 256,
                                                 lengths, len_add, S, enc);
    }
}

// ---------------------------------------------------------------------------
extern "C" void kernel_launch(void* const* d_in, const int* in_sizes, int n_in,
                              void* d_out, int out_size, void* d_ws, size_t ws_size,
                              hipStream_t stream)
{
    const float* x        = (const float*)d_in[0];
    const float* h0       = (const float*)d_in[1];
    const float* m        = (const float*)d_in[2];
    const float* dd       = (const float*)d_in[3];
    const float* x_m      = (const float*)d_in[4];
    const float* age      = (const float*)d_in[5];
    const float* gen      = (const float*)d_in[6];
    // d_in[7] = input_lengths (unused by reference)
    const int*   txts     = (const int*)d_in[8];
    const int*   txt_len  = (const int*)d_in[9];
    const float* dec_w    = (const float*)d_in[10];
    const float* dec_b    = (const float*)d_in[11];
    const float* hd_W     = (const float*)d_in[12];
    const float* hd_b     = (const float*)d_in[13];
    const float* gru_Wih  = (const float*)d_in[14];
    const float* gru_Whh  = (const float*)d_in[15];
    const float* gru_bih  = (const float*)d_in[16];
    const float* gru_bhh  = (const float*)d_in[17];
    const float* txt_emb  = (const float*)d_in[18];
    const float* t_in_W   = (const float*)d_in[19];
    const float* t_in_b   = (const float*)d_in[20];
    const float* t_attn_W = (const float*)d_in[21];
    const float* t_attn_b = (const float*)d_in[22];
    const float* t_ff_W1  = (const float*)d_in[23];
    const float* t_ff_b1  = (const float*)d_in[24];
    const float* t_ff_W2  = (const float*)d_in[25];
    const float* t_ff_b2  = (const float*)d_in[26];
    const float* t_ln_g   = (const float*)d_in[27];
    const float* t_ln_b   = (const float*)d_in[28];
    const float* f_in_W   = (const float*)d_in[29];
    const float* f_in_b   = (const float*)d_in[30];
    const float* f_attn_W = (const float*)d_in[31];
    const float* f_attn_b = (const float*)d_in[32];
    const float* f_ff_W1  = (const float*)d_in[33];
    const float* f_ff_b1  = (const float*)d_in[34];
    const float* f_ff_W2  = (const float*)d_in[35];
    const float* f_ff_b2  = (const float*)d_in[36];
    const float* f_ln_g   = (const float*)d_in[37];
    const float* f_ln_b   = (const float*)d_in[38];
    const float* f_cls    = (const float*)d_in[39];
    const float* fc1_W    = (const float*)d_in[40];
    const float* fc1_b    = (const float*)d_in[41];
    const float* bn_g     = (const float*)d_in[42];
    const float* bn_b     = (const float*)d_in[43];
    const float* fc2_W    = (const float*)d_in[44];
    const float* fc2_b    = (const float*)d_in[45];
    float* outp = (float*)d_out;

    // Workspace layout (floats)
    const size_t O_PE   = 0;                       // 153*256 -> pad 40960
    const size_t O_WHHT = 40960;                   // 256*768 = 196608
    const size_t O_EMB  = O_WHHT + 196608;         // 256*24*256 = 1572864
    const size_t O_ENCT = O_EMB + 1572864;         // 256*128*256 = 8388608
    const size_t O_ENCF = O_ENCT + 8388608;        // 256*153*256 = 10027008
    const size_t O_SCR  = O_ENCF + 10027008;       // max(qkv 39168*768, ff1 39168*512) = 30081024
    const size_t O_CTX  = O_SCR + 30081024;        // 10027008  (A-staging + ctx + y2)
    const size_t TOTALF = O_CTX + 10027008;        // 60334080 floats = ~241.3 MB

    if (ws_size < TOTALF * sizeof(float)) {
        fprintf(stderr, "kernel_launch: ws_size %zu < required %zu bytes\n",
                ws_size, TOTALF * sizeof(float));
        return;
    }
    float* ws = (float*)d_ws;
    float* pe   = ws + O_PE;
    float* whhT = ws + O_WHHT;
    float* emb  = ws + O_EMB;
    float* encT = ws + O_ENCT;
    float* encF = ws + O_ENCF;
    float* scr  = ws + O_SCR;
    float* actx = ws + O_CTX;

    // Precompute tables
    pe_kernel<<<SEQ_F, 256, 0, stream>>>(pe);
    transpose_whh_kernel<<<768, 256, 0, stream>>>(gru_Whh, whhT);

    // GRU-D scan -> emb (B,T,D)
    grud_kernel<<<BB, 256, 0, stream>>>(x, h0, m, dd, x_m, dec_w, dec_b, hd_W, hd_b,
                                        gru_Wih, gru_bih, whhT, gru_bhh, emb);

    // Text encoder: gather -> actx, then encode -> encT
    gather_kernel<<<BB * SEQ_T, 256, 0, stream>>>(txts, txt_emb, actx);
    run_encoder(encT, actx, scr, pe, SEQ_T, t_in_W, t_in_b, t_attn_W, t_attn_b,
                t_ff_W1, t_ff_b1, t_ff_W2, t_ff_b2, t_ln_g, t_ln_b, txt_len, 0, stream);

    // Fusion encoder: build seq -> actx, encode -> encF (fin_len = txt_len + 25)
    build_seq_kernel<<<BB * SEQ_F, 256, 0, stream>>>(emb, encT, f_cls, actx);
    run_encoder(encF, actx, scr, pe, SEQ_F, f_in_W, f_in_b, f_attn_W, f_attn_b,
                f_ff_W1, f_ff_b1, f_ff_W2, f_ff_b2, f_ln_g, f_ln_b, txt_len, 25, stream);

    // Classifier heads -> d_out (12,256,1)
    classifier_kernel<<<dim3(12, BB), 64, 0, stream>>>(encF, age, gen, fc1_W, fc1_b,
                                                       bn_g, bn_b, fc2_W, fc2_b, outp);
}

// Round 2
// 1633.457 us; speedup vs baseline: 2.6946x; 2.6946x over previous
//
#include <hip/hip_runtime.h>
#include <cstdio>
#include <cstddef>

// Problem dims
#define BB    256
#define TT    24
#define NFEAT 12
#define DIM   256
#define NH    8
#define DKH   32
#define FFD   512
#define SEQ_T 128
#define SEQ_F 153
#define NLAY  2

typedef unsigned short u16;
typedef u16   __attribute__((ext_vector_type(8))) u16x8;
typedef short __attribute__((ext_vector_type(8))) s16x8;
typedef float __attribute__((ext_vector_type(4))) f32x4;

__device__ inline u16 f2bf(float f) {
    union { float f; unsigned u; } v; v.f = f;
    unsigned r = v.u + 0x7FFFu + ((v.u >> 16) & 1u);
    return (u16)(r >> 16);
}
__device__ inline float bf2f(u16 h) {
    union { unsigned u; float f; } v; v.u = ((unsigned)h) << 16;
    return v.f;
}

// ---------------------------------------------------------------------------
__global__ void cast_bf16_kernel(const float* __restrict__ in, u16* __restrict__ outp, int n) {
    int i = blockIdx.x * 256 + threadIdx.x;
    int stride = gridDim.x * 256;
    for (; i < n; i += stride) outp[i] = f2bf(in[i]);
}

// PE table
__global__ void pe_kernel(float* __restrict__ pe) {
    int s = blockIdx.x, i = threadIdx.x;
    float e = (float)(2 * (i / 2)) * (1.0f / 256.0f);
    float freq = expf(-e * 9.210340371976184f);
    float ang = (float)s * freq;
    pe[s * 256 + i] = (i & 1) ? cosf(ang) : sinf(ang);
}

// Transpose gru_Whh (768x256) -> (256x768)
__global__ void transpose_whh_kernel(const float* __restrict__ Whh, float* __restrict__ Wt) {
    int n = blockIdx.x, k = threadIdx.x;
    Wt[(size_t)k * 768 + n] = Whh[(size_t)n * 256 + k];
}

// ---------------------------------------------------------------------------
// GRU-D scan: one block (768 threads = one per gate-output) per batch element.
__global__ __launch_bounds__(768) void grud_kernel(
    const float* __restrict__ x, const float* __restrict__ h0,
    const float* __restrict__ m, const float* __restrict__ dd,
    const float* __restrict__ x_m,
    const float* __restrict__ dec_w, const float* __restrict__ dec_b,
    const float* __restrict__ hd_W, const float* __restrict__ hd_b,
    const float* __restrict__ Wih, const float* __restrict__ bih,
    const float* __restrict__ WhhT, const float* __restrict__ bhh,
    float* __restrict__ emb)
{
    int b = blockIdx.x;
    int tid = threadIdx.x;          // 0..767
    int gate = tid >> 8;            // 0=r 1=z 2=n
    int j = tid & 255;
    __shared__ float hcs[256], hdecs[256], r_s[256], z_s[256];
    __shared__ float dts[12], xcm[24];

    float wih[24];
#pragma unroll
    for (int i = 0; i < 24; i++) wih[i] = Wih[(size_t)tid * 24 + i];
    float bi = bih[tid], bh = bhh[tid];

    float hdw[12]; float hdb = 0.0f;
    if (tid < 256) {
#pragma unroll
        for (int i = 0; i < 12; i++) hdw[i] = hd_W[tid * 12 + i];
        hdb = hd_b[tid];
        hcs[tid] = h0[(size_t)b * 256 + tid];
    }
    __syncthreads();

    for (int t = 0; t < TT; t++) {
        if (tid < 12) {
            size_t idx = ((size_t)b * TT + t) * NFEAT + tid;
            float dv = dd[idx], xv = x[idx], mv = m[idx];
            float xd = expf(-fmaxf(dv * dec_w[tid] + dec_b[tid], 0.0f));
            dts[tid] = dv;
            xcm[tid] = mv * xv + (1.0f - mv) * xd * xv + (1.0f - mv) * (1.0f - xd) * x_m[tid];
            xcm[12 + tid] = mv;
        }
        __syncthreads();
        if (tid < 256) {
            float acc = hdb;
#pragma unroll
            for (int i = 0; i < 12; i++) acc += hdw[i] * dts[i];
            hdecs[tid] = expf(-fmaxf(acc, 0.0f)) * hcs[tid];
        }
        __syncthreads();
        float acc_i = bi;
#pragma unroll
        for (int i = 0; i < 24; i++) acc_i += wih[i] * xcm[i];
        float acc_h = bh;
#pragma unroll 8
        for (int k = 0; k < 256; k++) acc_h += WhhT[(size_t)k * 768 + tid] * hdecs[k];
        if (gate == 0) r_s[j] = 1.0f / (1.0f + expf(-(acc_i + acc_h)));
        else if (gate == 1) z_s[j] = 1.0f / (1.0f + expf(-(acc_i + acc_h)));
        __syncthreads();
        if (gate == 2) {
            float n = tanhf(acc_i + r_s[j] * acc_h);
            float hnew = (1.0f - z_s[j]) * n + z_s[j] * hdecs[j];
            hcs[j] = hnew;
            emb[((size_t)b * TT + t) * 256 + j] = hnew;
        }
        __syncthreads();
    }
}

// ---------------------------------------------------------------------------
// Embedding gather -> bf16
__global__ void gather_kernel(const int* __restrict__ txts, const float* __restrict__ txt_emb,
                              u16* __restrict__ outp) {
    int r = blockIdx.x, i = threadIdx.x;
    outp[(size_t)r * 256 + i] = f2bf(txt_emb[(size_t)txts[r] * 256 + i]);
}

// Build fusion sequence -> bf16: [cls, emb(24), encT(128)]
__global__ void build_seq_kernel(const float* __restrict__ emb, const float* __restrict__ encT,
                                 const float* __restrict__ fcls, u16* __restrict__ seq) {
    int r = blockIdx.x, i = threadIdx.x;
    int b = r / SEQ_F, s = r - b * SEQ_F;
    float v;
    if (s == 0)       v = fcls[i];
    else if (s < 25)  v = emb[((size_t)b * TT + (s - 1)) * 256 + i];
    else              v = encT[((size_t)b * SEQ_T + (s - 25)) * 256 + i];
    seq[(size_t)r * 256 + i] = f2bf(v);
}

// ---------------------------------------------------------------------------
// bf16 MFMA GEMM: C(M,N) = A(M,K) @ W(N,K)^T + bias. 128x128 tile, 4 waves,
// each wave 64x64 (4x4 fragments of 16x16x32). A,W bf16; C fp32 or bf16(+relu).
template <int OUT_BF16, int RELU>
__global__ __launch_bounds__(256) void gemm_bf16_kernel(
    const u16* __restrict__ A, const u16* __restrict__ W,
    const float* __restrict__ bias, void* __restrict__ Cout,
    int M, int N, int K)
{
    __shared__ u16 As[128 * 40];
    __shared__ u16 Bs[128 * 40];
    const int bm = blockIdx.y * 128, bn = blockIdx.x * 128;
    const int tid = threadIdx.x;
    const int w = tid >> 6, lane = tid & 63;
    const int wm = (w >> 1) * 64, wn = (w & 1) * 64;
    const int lr = tid >> 1, lc = (tid & 1) * 16;   // staging: row, col-half
    const int l15 = lane & 15, l16 = lane >> 4;
    f32x4 acc[4][4] = {};

    for (int k0 = 0; k0 < K; k0 += 32) {
        const u16* ga = A + (size_t)(bm + lr) * K + k0 + lc;
        const u16* gb = W + (size_t)(bn + lr) * K + k0 + lc;
        u16x8 a0 = *(const u16x8*)ga;
        u16x8 a1 = *(const u16x8*)(ga + 8);
        u16x8 b0 = *(const u16x8*)gb;
        u16x8 b1 = *(const u16x8*)(gb + 8);
        __syncthreads();   // previous iteration's frag reads done
        *(u16x8*)&As[lr * 40 + lc] = a0;  *(u16x8*)&As[lr * 40 + lc + 8] = a1;
        *(u16x8*)&Bs[lr * 40 + lc] = b0;  *(u16x8*)&Bs[lr * 40 + lc + 8] = b1;
        __syncthreads();
        s16x8 af[4], bfr[4];
#pragma unroll
        for (int i = 0; i < 4; i++)
            af[i] = *(const s16x8*)&As[(wm + i * 16 + l15) * 40 + l16 * 8];
#pragma unroll
        for (int i = 0; i < 4; i++)
            bfr[i] = *(const s16x8*)&Bs[(wn + i * 16 + l15) * 40 + l16 * 8];
#pragma unroll
        for (int mi = 0; mi < 4; mi++)
#pragma unroll
            for (int ni = 0; ni < 4; ni++)
                acc[mi][ni] = __builtin_amdgcn_mfma_f32_16x16x32_bf16(af[mi], bfr[ni], acc[mi][ni], 0, 0, 0);
    }
#pragma unroll
    for (int mi = 0; mi < 4; mi++)
#pragma unroll
        for (int ni = 0; ni < 4; ni++) {
            int col = bn + wn + ni * 16 + l15;
            float bv = bias[col];
#pragma unroll
            for (int r = 0; r < 4; r++) {
                int row = bm + wm + mi * 16 + l16 * 4 + r;
                float v = acc[mi][ni][r] + bv;
                if (RELU) v = fmaxf(v, 0.0f);
                if (OUT_BF16) ((u16*)Cout)[(size_t)row * N + col] = f2bf(v);
                else          ((float*)Cout)[(size_t)row * N + col] = v;
            }
        }
}

// ---------------------------------------------------------------------------
// LayerNorm(row)*g+b + PE[s]  -> enc fp32 + enc bf16
__global__ __launch_bounds__(64) void ln_pe_kernel(
    const float* __restrict__ y, const float* __restrict__ g, const float* __restrict__ b,
    const float* __restrict__ pe, float* __restrict__ outp, u16* __restrict__ outb, int S)
{
    int r = blockIdx.x, t = threadIdx.x;
    const float* yr = y + (size_t)r * 256;
    float v[4]; float s = 0.0f;
#pragma unroll
    for (int i = 0; i < 4; i++) { v[i] = yr[t + 64 * i]; s += v[i]; }
#pragma unroll
    for (int o = 32; o >= 1; o >>= 1) s += __shfl_xor(s, o, 64);
    float mean = s * (1.0f / 256.0f);
    float vs = 0.0f;
#pragma unroll
    for (int i = 0; i < 4; i++) { float dlt = v[i] - mean; vs += dlt * dlt; }
#pragma unroll
    for (int o = 32; o >= 1; o >>= 1) vs += __shfl_xor(vs, o, 64);
    float rstd = rsqrtf(vs * (1.0f / 256.0f) + 1e-5f);
    int srow = r % S;
#pragma unroll
    for (int i = 0; i < 4; i++) {
        int c = t + 64 * i;
        float o = (v[i] - mean) * rstd * g[c] + b[c] + pe[srow * 256 + c];
        outp[(size_t)r * 256 + c] = o;
        outb[(size_t)r * 256 + c] = f2bf(o);
    }
}

// LayerNorm(y+res)*g+b * npad -> enc fp32 + bf16 (out may alias res)
__global__ __launch_bounds__(64) void add_ln_mask_kernel(
    const float* __restrict__ y, const float* __restrict__ res,
    const float* __restrict__ g, const float* __restrict__ b,
    const int* __restrict__ lengths, int len_add, int S,
    float* __restrict__ outp, u16* __restrict__ outb)
{
    int r = blockIdx.x, t = threadIdx.x;
    int bb = r / S, srow = r - bb * S;
    float mask = (srow < lengths[bb] + len_add) ? 1.0f : 0.0f;
    float v[4]; float s = 0.0f;
#pragma unroll
    for (int i = 0; i < 4; i++) {
        v[i] = y[(size_t)r * 256 + t + 64 * i] + res[(size_t)r * 256 + t + 64 * i];
        s += v[i];
    }
#pragma unroll
    for (int o = 32; o >= 1; o >>= 1) s += __shfl_xor(s, o, 64);
    float mean = s * (1.0f / 256.0f);
    float vs = 0.0f;
#pragma unroll
    for (int i = 0; i < 4; i++) { float dlt = v[i] - mean; vs += dlt * dlt; }
#pragma unroll
    for (int o = 32; o >= 1; o >>= 1) vs += __shfl_xor(vs, o, 64);
    float rstd = rsqrtf(vs * (1.0f / 256.0f) + 1e-5f);
#pragma unroll
    for (int i = 0; i < 4; i++) {
        int c = t + 64 * i;
        float o = ((v[i] - mean) * rstd * g[c] + b[c]) * mask;
        outp[(size_t)r * 256 + c] = o;
        outb[(size_t)r * 256 + c] = f2bf(o);
    }
}

// ---------------------------------------------------------------------------
// Fused attention: one block per (b,h); bf16 qkv in, bf16 ctx out.
__global__ __launch_bounds__(192) void attn_kernel(
    const u16* __restrict__ qkv, u16* __restrict__ ctx,
    const int* __restrict__ lengths, int len_add, int S)
{
    __shared__ float Ks[SEQ_F][32];
    __shared__ float Vs[SEQ_F][32];
    int bh = blockIdx.x;
    int b = bh >> 3, h = bh & 7;
    int tid = threadIdx.x;
    int len = lengths[b] + len_add;
    for (int idx = tid; idx < S * 32; idx += 192) {
        int s = idx >> 5, d2 = idx & 31;
        size_t base = ((size_t)(b * S + s)) * 768 + h * 32 + d2;
        Ks[s][d2] = bf2f(qkv[base + 256]);
        Vs[s][d2] = bf2f(qkv[base + 512]);
    }
    __syncthreads();
    if (tid < S) {
        float q[32];
        size_t qb = ((size_t)(b * S + tid)) * 768 + h * 32;
#pragma unroll
        for (int d2 = 0; d2 < 32; d2++) q[d2] = bf2f(qkv[qb + d2]) * 0.17677669529663687f;
        float mmax = -1e30f;
        for (int k2 = 0; k2 < len; k2++) {
            float sc = 0.0f;
#pragma unroll
            for (int d2 = 0; d2 < 32; d2++) sc += q[d2] * Ks[k2][d2];
            mmax = fmaxf(mmax, sc);
        }
        float l = 0.0f;
        float cacc[32] = {};
        for (int k2 = 0; k2 < len; k2++) {
            float sc = 0.0f;
#pragma unroll
            for (int d2 = 0; d2 < 32; d2++) sc += q[d2] * Ks[k2][d2];
            float p = expf(sc - mmax);
            l += p;
#pragma unroll
            for (int d2 = 0; d2 < 32; d2++) cacc[d2] += p * Vs[k2][d2];
        }
        float inv = 1.0f / l;
        size_t ob = ((size_t)(b * S + tid)) * 256 + h * 32;
#pragma unroll
        for (int d2 = 0; d2 < 32; d2++) ctx[ob + d2] = f2bf(cacc[d2] * inv);
    }
}

// ---------------------------------------------------------------------------
__global__ __launch_bounds__(64) void classifier_kernel(
    const float* __restrict__ encF, const float* __restrict__ age, const float* __restrict__ gen,
    const float* __restrict__ fc1_W, const float* __restrict__ fc1_b,
    const float* __restrict__ bn_g, const float* __restrict__ bn_b,
    const float* __restrict__ fc2_W, const float* __restrict__ fc2_b,
    float* __restrict__ outp)
{
    int k = blockIdx.x, b = blockIdx.y, t = threadIdx.x;
    const float* cls = encF + (size_t)b * SEQ_F * 256;
    const float* wrow = fc1_W + ((size_t)k * 64 + t) * 258;
    float acc = fc1_b[k * 64 + t];
    for (int d2 = 0; d2 < 256; d2++) acc += cls[d2] * wrow[d2];
    acc += age[b] * wrow[256] + gen[b] * wrow[257];
    const float RSQ = 0.99999500003749980e0f;
    acc = acc * RSQ * bn_g[k * 64 + t] + bn_b[k * 64 + t];
    acc = fmaxf(acc, 0.0f);
    float p = acc * fc2_W[k * 64 + t];
#pragma unroll
    for (int o = 32; o >= 1; o >>= 1) p += __shfl_xor(p, o, 64);
    if (t == 0) outp[k * 256 + b] = 1.0f / (1.0f + expf(-(p + fc2_b[k])));
}

// ---------------------------------------------------------------------------
struct WB { const u16 *inW, *attnW, *ff1W, *ff2W; };

static void run_encoder(float* enc, u16* enc_bf,
                        u16* actx_b, float* actx_f,
                        float* scr_f, u16* scr_b,
                        const WB& wb, const float* pe, int S,
                        const float* in_b, const float* attn_b,
                        const float* ff_b1, const float* ff_b2,
                        const float* ln_g, const float* ln_b,
                        const int* lengths, int len_add, hipStream_t stream)
{
    int M = BB * S;
    dim3 g256(256 / 128, M / 128), g512(512 / 128, M / 128), g768(768 / 128, M / 128);
    // input projection (A = actx_b bf16) -> scr_f fp32; LN+PE -> enc, enc_bf
    gemm_bf16_kernel<0, 0><<<g256, 256, 0, stream>>>(actx_b, wb.inW, in_b, scr_f, M, 256, 256);
    ln_pe_kernel<<<M, 64, 0, stream>>>(scr_f, ln_g, ln_b, pe, enc, enc_bf, S);
    for (int l = 0; l < NLAY; l++) {
        const u16* wqkv = wb.attnW + (size_t)l * 4 * 65536;
        const u16* wout = wb.attnW + ((size_t)l * 4 + 3) * 65536;
        const float* bqkv = attn_b + (size_t)l * 4 * 256;
        const float* bout = attn_b + ((size_t)l * 4 + 3) * 256;
        // qkv (bf16 out) -> scr_b
        gemm_bf16_kernel<1, 0><<<g768, 256, 0, stream>>>(enc_bf, wqkv, bqkv, scr_b, M, 768, 256);
        // attention -> ctx (bf16, actx_b)
        attn_kernel<<<BB * NH, 192, 0, stream>>>(scr_b, actx_b, lengths, len_add, S);
        // out proj -> scr_f fp32
        gemm_bf16_kernel<0, 0><<<g256, 256, 0, stream>>>(actx_b, wout, bout, scr_f, M, 256, 256);
        add_ln_mask_kernel<<<M, 64, 0, stream>>>(scr_f, enc, ln_g + (1 + 2 * l) * 256, ln_b + (1 + 2 * l) * 256,
                                                 lengths, len_add, S, enc, enc_bf);
        // ff1 (relu, bf16 out) -> scr_b
        gemm_bf16_kernel<1, 1><<<g512, 256, 0, stream>>>(enc_bf, wb.ff1W + (size_t)l * 512 * 256,
                                                         ff_b1 + l * 512, scr_b, M, 512, 256);
        // ff2 -> actx_f fp32
        gemm_bf16_kernel<0, 0><<<g256, 256, 0, stream>>>(scr_b, wb.ff2W + (size_t)l * 256 * 512,
                                                         ff_b2 + l * 256, actx_f, M, 256, 512);
        add_ln_mask_kernel<<<M, 64, 0, stream>>>(actx_f, enc, ln_g + (2 + 2 * l) * 256, ln_b + (2 + 2 * l) * 256,
                                                 lengths, len_add, S, enc, enc_bf);
    }
}

// ---------------------------------------------------------------------------
extern "C" void kernel_launch(void* const* d_in, const int* in_sizes, int n_in,
                              void* d_out, int out_size, void* d_ws, size_t ws_size,
                              hipStream_t stream)
{
    const float* x        = (const float*)d_in[0];
    const float* h0       = (const float*)d_in[1];
    const float* m        = (const float*)d_in[2];
    const float* dd       = (const float*)d_in[3];
    const float* x_m      = (const float*)d_in[4];
    const float* age      = (const float*)d_in[5];
    const float* gen      = (const float*)d_in[6];
    const int*   txts     = (const int*)d_in[8];
    const int*   txt_len  = (const int*)d_in[9];
    const float* dec_w    = (const float*)d_in[10];
    const float* dec_b    = (const float*)d_in[11];
    const float* hd_W     = (const float*)d_in[12];
    const float* hd_b     = (const float*)d_in[13];
    const float* gru_Wih  = (const float*)d_in[14];
    const float* gru_Whh  = (const float*)d_in[15];
    const float* gru_bih  = (const float*)d_in[16];
    const float* gru_bhh  = (const float*)d_in[17];
    const float* txt_emb  = (const float*)d_in[18];
    const float* t_in_W   = (const float*)d_in[19];
    const float* t_in_b   = (const float*)d_in[20];
    const float* t_attn_W = (const float*)d_in[21];
    const float* t_attn_b = (const float*)d_in[22];
    const float* t_ff_W1  = (const float*)d_in[23];
    const float* t_ff_b1  = (const float*)d_in[24];
    const float* t_ff_W2  = (const float*)d_in[25];
    const float* t_ff_b2  = (const float*)d_in[26];
    const float* t_ln_g   = (const float*)d_in[27];
    const float* t_ln_b   = (const float*)d_in[28];
    const float* f_in_W   = (const float*)d_in[29];
    const float* f_in_b   = (const float*)d_in[30];
    const float* f_attn_W = (const float*)d_in[31];
    const float* f_attn_b = (const float*)d_in[32];
    const float* f_ff_W1  = (const float*)d_in[33];
    const float* f_ff_b1  = (const float*)d_in[34];
    const float* f_ff_W2  = (const float*)d_in[35];
    const float* f_ff_b2  = (const float*)d_in[36];
    const float* f_ln_g   = (const float*)d_in[37];
    const float* f_ln_b   = (const float*)d_in[38];
    const float* f_cls    = (const float*)d_in[39];
    const float* fc1_W    = (const float*)d_in[40];
    const float* fc1_b    = (const float*)d_in[41];
    const float* bn_g     = (const float*)d_in[42];
    const float* bn_b     = (const float*)d_in[43];
    const float* fc2_W    = (const float*)d_in[44];
    const float* fc2_b    = (const float*)d_in[45];
    float* outp = (float*)d_out;

    // Workspace layout (float units)
    const size_t O_PE    = 0;                        // 40960
    const size_t O_WHHT  = 40960;                    // 196608
    const size_t O_EMB   = 237568;                   // 1572864
    const size_t O_ENCT  = 1810432;                  // 8388608
    const size_t O_ENCF  = 10199040;                 // 10027008
    const size_t O_SCR   = 20226048;                 // 15040512 (qkv bf16 / y fp32 / ff1 bf16)
    const size_t O_ACTX  = 35266560;                 // 10027008 (A-bf16 / ctx-bf16 / y2 fp32)
    const size_t O_ENCBF = 45293568;                 // 5013504  (39168*256 bf16)
    const size_t O_WBF   = 50307072;                 // 1114112  (2228224 bf16)
    const size_t TOTALF  = 51421184;                 // ~205.7 MB

    if (ws_size < TOTALF * sizeof(float)) {
        fprintf(stderr, "kernel_launch: ws_size %zu < required %zu bytes\n",
                ws_size, TOTALF * sizeof(float));
        return;
    }
    float* ws    = (float*)d_ws;
    float* pe    = ws + O_PE;
    float* whhT  = ws + O_WHHT;
    float* emb   = ws + O_EMB;
    float* encT  = ws + O_ENCT;
    float* encF  = ws + O_ENCF;
    float* scr_f = ws + O_SCR;   u16* scr_b  = (u16*)scr_f;
    float* actx_f= ws + O_ACTX;  u16* actx_b = (u16*)actx_f;
    u16*   encbf = (u16*)(ws + O_ENCBF);
    u16*   wbf   = (u16*)(ws + O_WBF);

    // bf16 weight casts (per encoder: inW 65536 | attnW 524288 | ff1 262144 | ff2 262144)
    const size_t PER_ENC = 1114112;
    struct { const float* src; size_t off; int n; } casts[8] = {
        { t_in_W,   0,               65536  },
        { t_attn_W, 65536,           524288 },
        { t_ff_W1,  589824,          262144 },
        { t_ff_W2,  851968,          262144 },
        { f_in_W,   PER_ENC + 0,     65536  },
        { f_attn_W, PER_ENC + 65536, 524288 },
        { f_ff_W1,  PER_ENC + 589824, 262144 },
        { f_ff_W2,  PER_ENC + 851968, 262144 },
    };
    for (int i = 0; i < 8; i++)
        cast_bf16_kernel<<<(casts[i].n + 255) / 256, 256, 0, stream>>>(casts[i].src, wbf + casts[i].off, casts[i].n);

    WB wbT = { wbf + 0, wbf + 65536, wbf + 589824, wbf + 851968 };
    WB wbF = { wbf + PER_ENC, wbf + PER_ENC + 65536, wbf + PER_ENC + 589824, wbf + PER_ENC + 851968 };

    pe_kernel<<<SEQ_F, 256, 0, stream>>>(pe);
    transpose_whh_kernel<<<768, 256, 0, stream>>>(gru_Whh, whhT);

    grud_kernel<<<BB, 768, 0, stream>>>(x, h0, m, dd, x_m, dec_w, dec_b, hd_W, hd_b,
                                        gru_Wih, gru_bih, whhT, gru_bhh, emb);

    // Text encoder
    gather_kernel<<<BB * SEQ_T, 256, 0, stream>>>(txts, txt_emb, actx_b);
    run_encoder(encT, encbf, actx_b, actx_f, scr_f, scr_b, wbT, pe, SEQ_T,
                t_in_b, t_attn_b, t_ff_b1, t_ff_b2, t_ln_g, t_ln_b, txt_len, 0, stream);

    // Fusion encoder
    build_seq_kernel<<<BB * SEQ_F, 256, 0, stream>>>(emb, encT, f_cls, actx_b);
    run_encoder(encF, encbf, actx_b, actx_f, scr_f, scr_b, wbF, pe, SEQ_F,
                f_in_b, f_attn_b, f_ff_b1, f_ff_b2, f_ln_g, f_ln_b, txt_len, 25, stream);

    classifier_kernel<<<dim3(12, BB), 64, 0, stream>>>(encF, age, gen, fc1_W, fc1_b,
                                                       bn_g, bn_b, fc2_W, fc2_b, outp);
}

// Round 3
// 1048.532 us; speedup vs baseline: 4.1978x; 1.5579x over previous
//
#include <hip/hip_runtime.h>
#include <cstdio>
#include <cstddef>

// Problem dims
#define BB    256
#define TT    24
#define NFEAT 12
#define DIM   256
#define NH    8
#define DKH   32
#define FFD   512
#define SEQ_T 128
#define SEQ_F 153
#define NLAY  2

typedef unsigned short u16;
typedef u16   __attribute__((ext_vector_type(8))) u16x8;
typedef short __attribute__((ext_vector_type(8))) s16x8;
typedef float __attribute__((ext_vector_type(4))) f32x4;

__device__ inline u16 f2bf(float f) {
    union { float f; unsigned u; } v; v.f = f;
    unsigned r = v.u + 0x7FFFu + ((v.u >> 16) & 1u);
    return (u16)(r >> 16);
}
__device__ inline float bf2f(u16 h) {
    union { unsigned u; float f; } v; v.u = ((unsigned)h) << 16;
    return v.f;
}

// ---------------------------------------------------------------------------
__global__ void cast_bf16_kernel(const float* __restrict__ in, u16* __restrict__ outp, int n) {
    int i = blockIdx.x * 256 + threadIdx.x;
    int stride = gridDim.x * 256;
    for (; i < n; i += stride) outp[i] = f2bf(in[i]);
}

// PE table
__global__ void pe_kernel(float* __restrict__ pe) {
    int s = blockIdx.x, i = threadIdx.x;
    float e = (float)(2 * (i / 2)) * (1.0f / 256.0f);
    float freq = expf(-e * 9.210340371976184f);
    float ang = (float)s * freq;
    pe[s * 256 + i] = (i & 1) ? cosf(ang) : sinf(ang);
}

// Transpose gru_Whh (768x256) -> (256x768)
__global__ void transpose_whh_kernel(const float* __restrict__ Whh, float* __restrict__ Wt) {
    int n = blockIdx.x, k = threadIdx.x;
    Wt[(size_t)k * 768 + n] = Whh[(size_t)n * 256 + k];
}

// ---------------------------------------------------------------------------
// GRU-D scan: one block (768 threads = one per gate-output) per batch element.
__global__ __launch_bounds__(768) void grud_kernel(
    const float* __restrict__ x, const float* __restrict__ h0,
    const float* __restrict__ m, const float* __restrict__ dd,
    const float* __restrict__ x_m,
    const float* __restrict__ dec_w, const float* __restrict__ dec_b,
    const float* __restrict__ hd_W, const float* __restrict__ hd_b,
    const float* __restrict__ Wih, const float* __restrict__ bih,
    const float* __restrict__ WhhT, const float* __restrict__ bhh,
    float* __restrict__ emb)
{
    int b = blockIdx.x;
    int tid = threadIdx.x;          // 0..767
    int gate = tid >> 8;            // 0=r 1=z 2=n
    int j = tid & 255;
    __shared__ float hcs[256], hdecs[256], r_s[256], z_s[256];
    __shared__ float dts[12], xcm[24];

    float wih[24];
#pragma unroll
    for (int i = 0; i < 24; i++) wih[i] = Wih[(size_t)tid * 24 + i];
    float bi = bih[tid], bh = bhh[tid];

    float hdw[12]; float hdb = 0.0f;
    if (tid < 256) {
#pragma unroll
        for (int i = 0; i < 12; i++) hdw[i] = hd_W[tid * 12 + i];
        hdb = hd_b[tid];
        hcs[tid] = h0[(size_t)b * 256 + tid];
    }
    __syncthreads();

    for (int t = 0; t < TT; t++) {
        if (tid < 12) {
            size_t idx = ((size_t)b * TT + t) * NFEAT + tid;
            float dv = dd[idx], xv = x[idx], mv = m[idx];
            float xd = expf(-fmaxf(dv * dec_w[tid] + dec_b[tid], 0.0f));
            dts[tid] = dv;
            xcm[tid] = mv * xv + (1.0f - mv) * xd * xv + (1.0f - mv) * (1.0f - xd) * x_m[tid];
            xcm[12 + tid] = mv;
        }
        __syncthreads();
        if (tid < 256) {
            float acc = hdb;
#pragma unroll
            for (int i = 0; i < 12; i++) acc += hdw[i] * dts[i];
            hdecs[tid] = expf(-fmaxf(acc, 0.0f)) * hcs[tid];
        }
        __syncthreads();
        float acc_i = bi;
#pragma unroll
        for (int i = 0; i < 24; i++) acc_i += wih[i] * xcm[i];
        float acc_h = bh;
#pragma unroll 8
        for (int k = 0; k < 256; k++) acc_h += WhhT[(size_t)k * 768 + tid] * hdecs[k];
        if (gate == 0) r_s[j] = 1.0f / (1.0f + expf(-(acc_i + acc_h)));
        else if (gate == 1) z_s[j] = 1.0f / (1.0f + expf(-(acc_i + acc_h)));
        __syncthreads();
        if (gate == 2) {
            float n = tanhf(acc_i + r_s[j] * acc_h);
            float hnew = (1.0f - z_s[j]) * n + z_s[j] * hdecs[j];
            hcs[j] = hnew;
            emb[((size_t)b * TT + t) * 256 + j] = hnew;
        }
        __syncthreads();
    }
}

// ---------------------------------------------------------------------------
// Embedding gather -> bf16
__global__ void gather_kernel(const int* __restrict__ txts, const float* __restrict__ txt_emb,
                              u16* __restrict__ outp) {
    int r = blockIdx.x, i = threadIdx.x;
    outp[(size_t)r * 256 + i] = f2bf(txt_emb[(size_t)txts[r] * 256 + i]);
}

// Build fusion sequence -> bf16: [cls, emb(24), encT(128)]
__global__ void build_seq_kernel(const float* __restrict__ emb, const float* __restrict__ encT,
                                 const float* __restrict__ fcls, u16* __restrict__ seq) {
    int r = blockIdx.x, i = threadIdx.x;
    int b = r / SEQ_F, s = r - b * SEQ_F;
    float v;
    if (s == 0)       v = fcls[i];
    else if (s < 25)  v = emb[((size_t)b * TT + (s - 1)) * 256 + i];
    else              v = encT[((size_t)b * SEQ_T + (s - 25)) * 256 + i];
    seq[(size_t)r * 256 + i] = f2bf(v);
}

// ---------------------------------------------------------------------------
// bf16 MFMA GEMM: C(M,N) = A(M,K) @ W(N,K)^T + bias. 128x128 tile, 4 waves,
// each wave 64x64 (4x4 fragments of 16x16x32). A,W bf16; C fp32 or bf16(+relu).
template <int OUT_BF16, int RELU>
__global__ __launch_bounds__(256) void gemm_bf16_kernel(
    const u16* __restrict__ A, const u16* __restrict__ W,
    const float* __restrict__ bias, void* __restrict__ Cout,
    int M, int N, int K)
{
    __shared__ u16 As[128 * 40];
    __shared__ u16 Bs[128 * 40];
    const int bm = blockIdx.y * 128, bn = blockIdx.x * 128;
    const int tid = threadIdx.x;
    const int w = tid >> 6, lane = tid & 63;
    const int wm = (w >> 1) * 64, wn = (w & 1) * 64;
    const int lr = tid >> 1, lc = (tid & 1) * 16;   // staging: row, col-half
    const int l15 = lane & 15, l16 = lane >> 4;
    f32x4 acc[4][4] = {};

    for (int k0 = 0; k0 < K; k0 += 32) {
        const u16* ga = A + (size_t)(bm + lr) * K + k0 + lc;
        const u16* gb = W + (size_t)(bn + lr) * K + k0 + lc;
        u16x8 a0 = *(const u16x8*)ga;
        u16x8 a1 = *(const u16x8*)(ga + 8);
        u16x8 b0 = *(const u16x8*)gb;
        u16x8 b1 = *(const u16x8*)(gb + 8);
        __syncthreads();   // previous iteration's frag reads done
        *(u16x8*)&As[lr * 40 + lc] = a0;  *(u16x8*)&As[lr * 40 + lc + 8] = a1;
        *(u16x8*)&Bs[lr * 40 + lc] = b0;  *(u16x8*)&Bs[lr * 40 + lc + 8] = b1;
        __syncthreads();
        s16x8 af[4], bfr[4];
#pragma unroll
        for (int i = 0; i < 4; i++)
            af[i] = *(const s16x8*)&As[(wm + i * 16 + l15) * 40 + l16 * 8];
#pragma unroll
        for (int i = 0; i < 4; i++)
            bfr[i] = *(const s16x8*)&Bs[(wn + i * 16 + l15) * 40 + l16 * 8];
#pragma unroll
        for (int mi = 0; mi < 4; mi++)
#pragma unroll
            for (int ni = 0; ni < 4; ni++)
                acc[mi][ni] = __builtin_amdgcn_mfma_f32_16x16x32_bf16(af[mi], bfr[ni], acc[mi][ni], 0, 0, 0);
    }
#pragma unroll
    for (int mi = 0; mi < 4; mi++)
#pragma unroll
        for (int ni = 0; ni < 4; ni++) {
            int col = bn + wn + ni * 16 + l15;
            float bv = bias[col];
#pragma unroll
            for (int r = 0; r < 4; r++) {
                int row = bm + wm + mi * 16 + l16 * 4 + r;
                float v = acc[mi][ni][r] + bv;
                if (RELU) v = fmaxf(v, 0.0f);
                if (OUT_BF16) ((u16*)Cout)[(size_t)row * N + col] = f2bf(v);
                else          ((float*)Cout)[(size_t)row * N + col] = v;
            }
        }
}

// ---------------------------------------------------------------------------
// LayerNorm(row)*g+b + PE[s]  -> enc fp32 + enc bf16
__global__ __launch_bounds__(64) void ln_pe_kernel(
    const float* __restrict__ y, const float* __restrict__ g, const float* __restrict__ b,
    const float* __restrict__ pe, float* __restrict__ outp, u16* __restrict__ outb, int S)
{
    int r = blockIdx.x, t = threadIdx.x;
    const float* yr = y + (size_t)r * 256;
    float v[4]; float s = 0.0f;
#pragma unroll
    for (int i = 0; i < 4; i++) { v[i] = yr[t + 64 * i]; s += v[i]; }
#pragma unroll
    for (int o = 32; o >= 1; o >>= 1) s += __shfl_xor(s, o, 64);
    float mean = s * (1.0f / 256.0f);
    float vs = 0.0f;
#pragma unroll
    for (int i = 0; i < 4; i++) { float dlt = v[i] - mean; vs += dlt * dlt; }
#pragma unroll
    for (int o = 32; o >= 1; o >>= 1) vs += __shfl_xor(vs, o, 64);
    float rstd = rsqrtf(vs * (1.0f / 256.0f) + 1e-5f);
    int srow = r % S;
#pragma unroll
    for (int i = 0; i < 4; i++) {
        int c = t + 64 * i;
        float o = (v[i] - mean) * rstd * g[c] + b[c] + pe[srow * 256 + c];
        outp[(size_t)r * 256 + c] = o;
        outb[(size_t)r * 256 + c] = f2bf(o);
    }
}

// LayerNorm(y+res)*g+b * npad -> enc fp32 + bf16 (out may alias res)
__global__ __launch_bounds__(64) void add_ln_mask_kernel(
    const float* __restrict__ y, const float* __restrict__ res,
    const float* __restrict__ g, const float* __restrict__ b,
    const int* __restrict__ lengths, int len_add, int S,
    float* __restrict__ outp, u16* __restrict__ outb)
{
    int r = blockIdx.x, t = threadIdx.x;
    int bb = r / S, srow = r - bb * S;
    float mask = (srow < lengths[bb] + len_add) ? 1.0f : 0.0f;
    float v[4]; float s = 0.0f;
#pragma unroll
    for (int i = 0; i < 4; i++) {
        v[i] = y[(size_t)r * 256 + t + 64 * i] + res[(size_t)r * 256 + t + 64 * i];
        s += v[i];
    }
#pragma unroll
    for (int o = 32; o >= 1; o >>= 1) s += __shfl_xor(s, o, 64);
    float mean = s * (1.0f / 256.0f);
    float vs = 0.0f;
#pragma unroll
    for (int i = 0; i < 4; i++) { float dlt = v[i] - mean; vs += dlt * dlt; }
#pragma unroll
    for (int o = 32; o >= 1; o >>= 1) vs += __shfl_xor(vs, o, 64);
    float rstd = rsqrtf(vs * (1.0f / 256.0f) + 1e-5f);
#pragma unroll
    for (int i = 0; i < 4; i++) {
        int c = t + 64 * i;
        float o = ((v[i] - mean) * rstd * g[c] + b[c]) * mask;
        outp[(size_t)r * 256 + c] = o;
        outb[(size_t)r * 256 + c] = f2bf(o);
    }
}

// ---------------------------------------------------------------------------
// MFMA flash attention. Grid: (B*H*QT) blocks, 256 threads (4 waves).
// Wave w handles 16 query rows [qt*64 + w*16, +16). Online softmax, key tiles
// of 32 (one 16x16x32 MFMA per 16-key half; full dk=32 in one MFMA).
// Scores computed transposed: S^T = mfma(K, Q) -> lane holds 8 scores for
// query l15. PV: O^T = mfma(V^T, P^T), P routed through per-wave LDS tile.
__global__ __launch_bounds__(256) void attn_mfma_kernel(
    const u16* __restrict__ qkv, u16* __restrict__ ctx,
    const int* __restrict__ lengths, int len_add, int S, int QT)
{
    __shared__ u16 K_lds[160][40];    // [key][d], pad 40
    __shared__ u16 Vt_lds[32][168];   // [d][key], pad 168
    __shared__ u16 P_lds[4][16][40];  // per-wave [q][key-local]

    const int blk = blockIdx.x;
    const int qt = blk % QT;
    const int bh = blk / QT;
    const int b = bh >> 3, h = bh & 7;
    const int len = lengths[b] + len_add;
    const int tid = threadIdx.x;
    const int w = tid >> 6;
    const int lane = tid & 63;
    const int l15 = lane & 15, l16 = lane >> 4;

    // Stage K row-major and V transposed; zero-fill rows [S,160) (NaN safety).
    const u16* kbase = qkv + ((size_t)b * S) * 768 + 256 + h * 32;
    const u16* vbase = kbase + 256;
    for (int chunk = tid; chunk < 160 * 4; chunk += 256) {
        int s = chunk >> 2, d8 = (chunk & 3) * 8;
        u16x8 kv = {}; u16x8 vv = {};
        if (s < S) {
            kv = *(const u16x8*)(kbase + (size_t)s * 768 + d8);
            vv = *(const u16x8*)(vbase + (size_t)s * 768 + d8);
        }
        *(u16x8*)&K_lds[s][d8] = kv;
#pragma unroll
        for (int j = 0; j < 8; j++) Vt_lds[d8 + j][s] = vv[j];
    }

    // Q fragment: row = l15 (clamped), k = l16*8..+7
    const int q0 = qt * 64 + w * 16;
    const int qr = min(q0 + l15, S - 1);
    s16x8 qf = *(const s16x8*)(qkv + ((size_t)(b * S + qr)) * 768 + h * 32 + l16 * 8);

    const f32x4 zero4 = {0.0f, 0.0f, 0.0f, 0.0f};
    f32x4 o0 = zero4, o1 = zero4;          // O^T[d=l16*4+r(+16)][q=l15]
    float mreg = -1e30f, lreg = 0.0f;
    const float SCALE = 0.17677669529663687f;

    __syncthreads();

    for (int k0 = 0; k0 < len; k0 += 32) {
        s16x8 kf0 = *(const s16x8*)&K_lds[k0 + l15][l16 * 8];
        s16x8 kf1 = *(const s16x8*)&K_lds[k0 + 16 + l15][l16 * 8];
        f32x4 c0 = __builtin_amdgcn_mfma_f32_16x16x32_bf16(kf0, qf, zero4, 0, 0, 0);
        f32x4 c1 = __builtin_amdgcn_mfma_f32_16x16x32_bf16(kf1, qf, zero4, 0, 0, 0);
        // lane holds scores for query l15, keys k0 + l16*4+r and +16
        float sc[8];
#pragma unroll
        for (int r = 0; r < 4; r++) {
            int key0 = k0 + l16 * 4 + r;
            sc[r]     = (key0 < len)      ? c0[r] * SCALE : -1e30f;
            sc[4 + r] = (key0 + 16 < len) ? c1[r] * SCALE : -1e30f;
        }
        float tmax = sc[0];
#pragma unroll
        for (int i = 1; i < 8; i++) tmax = fmaxf(tmax, sc[i]);
        tmax = fmaxf(tmax, __shfl_xor(tmax, 16, 64));
        tmax = fmaxf(tmax, __shfl_xor(tmax, 32, 64));
        float mnew = fmaxf(mreg, tmax);
        float rescale = expf(mreg - mnew);
        float psum = 0.0f;
        u16 pb[8];
#pragma unroll
        for (int i = 0; i < 8; i++) {
            float p = expf(sc[i] - mnew);
            psum += p;
            pb[i] = f2bf(p);
        }
        psum += __shfl_xor(psum, 16, 64);
        psum += __shfl_xor(psum, 32, 64);
        lreg = lreg * rescale + psum;
        mreg = mnew;
#pragma unroll
        for (int i = 0; i < 4; i++) { o0[i] *= rescale; o1[i] *= rescale; }
        // P roundtrip (per-wave region; same-wave RAW handled by compiler waitcnt)
#pragma unroll
        for (int r = 0; r < 4; r++) {
            P_lds[w][l15][l16 * 4 + r]      = pb[r];
            P_lds[w][l15][16 + l16 * 4 + r] = pb[4 + r];
        }
        s16x8 pf  = *(const s16x8*)&P_lds[w][l15][l16 * 8];
        s16x8 vf0 = *(const s16x8*)&Vt_lds[l15][k0 + l16 * 8];
        s16x8 vf1 = *(const s16x8*)&Vt_lds[16 + l15][k0 + l16 * 8];
        o0 = __builtin_amdgcn_mfma_f32_16x16x32_bf16(vf0, pf, o0, 0, 0, 0);
        o1 = __builtin_amdgcn_mfma_f32_16x16x32_bf16(vf1, pf, o1, 0, 0, 0);
    }

    float inv = 1.0f / lreg;
    int qg = q0 + l15;
    if (qg < S) {
        size_t ob = ((size_t)(b * S + qg)) * 256 + h * 32;
#pragma unroll
        for (int r = 0; r < 4; r++) {
            ctx[ob + l16 * 4 + r]      = f2bf(o0[r] * inv);
            ctx[ob + 16 + l16 * 4 + r] = f2bf(o1[r] * inv);
        }
    }
}

// ---------------------------------------------------------------------------
__global__ __launch_bounds__(64) void classifier_kernel(
    const float* __restrict__ encF, const float* __restrict__ age, const float* __restrict__ gen,
    const float* __restrict__ fc1_W, const float* __restrict__ fc1_b,
    const float* __restrict__ bn_g, const float* __restrict__ bn_b,
    const float* __restrict__ fc2_W, const float* __restrict__ fc2_b,
    float* __restrict__ outp)
{
    int k = blockIdx.x, b = blockIdx.y, t = threadIdx.x;
    const float* cls = encF + (size_t)b * SEQ_F * 256;
    const float* wrow = fc1_W + ((size_t)k * 64 + t) * 258;
    float acc = fc1_b[k * 64 + t];
    for (int d2 = 0; d2 < 256; d2++) acc += cls[d2] * wrow[d2];
    acc += age[b] * wrow[256] + gen[b] * wrow[257];
    const float RSQ = 0.99999500003749980e0f;
    acc = acc * RSQ * bn_g[k * 64 + t] + bn_b[k * 64 + t];
    acc = fmaxf(acc, 0.0f);
    float p = acc * fc2_W[k * 64 + t];
#pragma unroll
    for (int o = 32; o >= 1; o >>= 1) p += __shfl_xor(p, o, 64);
    if (t == 0) outp[k * 256 + b] = 1.0f / (1.0f + expf(-(p + fc2_b[k])));
}

// ---------------------------------------------------------------------------
struct WB { const u16 *inW, *attnW, *ff1W, *ff2W; };

static void run_encoder(float* enc, u16* enc_bf,
                        u16* actx_b, float* actx_f,
                        float* scr_f, u16* scr_b,
                        const WB& wb, const float* pe, int S,
                        const float* in_b, const float* attn_b,
                        const float* ff_b1, const float* ff_b2,
                        const float* ln_g, const float* ln_b,
                        const int* lengths, int len_add, hipStream_t stream)
{
    int M = BB * S;
    int QT = (S + 63) / 64;
    dim3 g256(256 / 128, M / 128), g512(512 / 128, M / 128), g768(768 / 128, M / 128);
    // input projection (A = actx_b bf16) -> scr_f fp32; LN+PE -> enc, enc_bf
    gemm_bf16_kernel<0, 0><<<g256, 256, 0, stream>>>(actx_b, wb.inW, in_b, scr_f, M, 256, 256);
    ln_pe_kernel<<<M, 64, 0, stream>>>(scr_f, ln_g, ln_b, pe, enc, enc_bf, S);
    for (int l = 0; l < NLAY; l++) {
        const u16* wqkv = wb.attnW + (size_t)l * 4 * 65536;
        const u16* wout = wb.attnW + ((size_t)l * 4 + 3) * 65536;
        const float* bqkv = attn_b + (size_t)l * 4 * 256;
        const float* bout = attn_b + ((size_t)l * 4 + 3) * 256;
        // qkv (bf16 out) -> scr_b
        gemm_bf16_kernel<1, 0><<<g768, 256, 0, stream>>>(enc_bf, wqkv, bqkv, scr_b, M, 768, 256);
        // attention -> ctx (bf16, actx_b)
        attn_mfma_kernel<<<BB * NH * QT, 256, 0, stream>>>(scr_b, actx_b, lengths, len_add, S, QT);
        // out proj -> scr_f fp32
        gemm_bf16_kernel<0, 0><<<g256, 256, 0, stream>>>(actx_b, wout, bout, scr_f, M, 256, 256);
        add_ln_mask_kernel<<<M, 64, 0, stream>>>(scr_f, enc, ln_g + (1 + 2 * l) * 256, ln_b + (1 + 2 * l) * 256,
                                                 lengths, len_add, S, enc, enc_bf);
        // ff1 (relu, bf16 out) -> scr_b
        gemm_bf16_kernel<1, 1><<<g512, 256, 0, stream>>>(enc_bf, wb.ff1W + (size_t)l * 512 * 256,
                                                         ff_b1 + l * 512, scr_b, M, 512, 256);
        // ff2 -> actx_f fp32
        gemm_bf16_kernel<0, 0><<<g256, 256, 0, stream>>>(scr_b, wb.ff2W + (size_t)l * 256 * 512,
                                                         ff_b2 + l * 256, actx_f, M, 256, 512);
        add_ln_mask_kernel<<<M, 64, 0, stream>>>(actx_f, enc, ln_g + (2 + 2 * l) * 256, ln_b + (2 + 2 * l) * 256,
                                                 lengths, len_add, S, enc, enc_bf);
    }
}

// ---------------------------------------------------------------------------
extern "C" void kernel_launch(void* const* d_in, const int* in_sizes, int n_in,
                              void* d_out, int out_size, void* d_ws, size_t ws_size,
                              hipStream_t stream)
{
    const float* x        = (const float*)d_in[0];
    const float* h0       = (const float*)d_in[1];
    const float* m        = (const float*)d_in[2];
    const float* dd       = (const float*)d_in[3];
    const float* x_m      = (const float*)d_in[4];
    const float* age      = (const float*)d_in[5];
    const float* gen      = (const float*)d_in[6];
    const int*   txts     = (const int*)d_in[8];
    const int*   txt_len  = (const int*)d_in[9];
    const float* dec_w    = (const float*)d_in[10];
    const float* dec_b    = (const float*)d_in[11];
    const float* hd_W     = (const float*)d_in[12];
    const float* hd_b     = (const float*)d_in[13];
    const float* gru_Wih  = (const float*)d_in[14];
    const float* gru_Whh  = (const float*)d_in[15];
    const float* gru_bih  = (const float*)d_in[16];
    const float* gru_bhh  = (const float*)d_in[17];
    const float* txt_emb  = (const float*)d_in[18];
    const float* t_in_W   = (const float*)d_in[19];
    const float* t_in_b   = (const float*)d_in[20];
    const float* t_attn_W = (const float*)d_in[21];
    const float* t_attn_b = (const float*)d_in[22];
    const float* t_ff_W1  = (const float*)d_in[23];
    const float* t_ff_b1  = (const float*)d_in[24];
    const float* t_ff_W2  = (const float*)d_in[25];
    const float* t_ff_b2  = (const float*)d_in[26];
    const float* t_ln_g   = (const float*)d_in[27];
    const float* t_ln_b   = (const float*)d_in[28];
    const float* f_in_W   = (const float*)d_in[29];
    const float* f_in_b   = (const float*)d_in[30];
    const float* f_attn_W = (const float*)d_in[31];
    const float* f_attn_b = (const float*)d_in[32];
    const float* f_ff_W1  = (const float*)d_in[33];
    const float* f_ff_b1  = (const float*)d_in[34];
    const float* f_ff_W2  = (const float*)d_in[35];
    const float* f_ff_b2  = (const float*)d_in[36];
    const float* f_ln_g   = (const float*)d_in[37];
    const float* f_ln_b   = (const float*)d_in[38];
    const float* f_cls    = (const float*)d_in[39];
    const float* fc1_W    = (const float*)d_in[40];
    const float* fc1_b    = (const float*)d_in[41];
    const float* bn_g     = (const float*)d_in[42];
    const float* bn_b     = (const float*)d_in[43];
    const float* fc2_W    = (const float*)d_in[44];
    const float* fc2_b    = (const float*)d_in[45];
    float* outp = (float*)d_out;

    // Workspace layout (float units)
    const size_t O_PE    = 0;                        // 40960
    const size_t O_WHHT  = 40960;                    // 196608
    const size_t O_EMB   = 237568;                   // 1572864
    const size_t O_ENCT  = 1810432;                  // 8388608
    const size_t O_ENCF  = 10199040;                 // 10027008
    const size_t O_SCR   = 20226048;                 // 15040512 (qkv bf16 / y fp32 / ff1 bf16)
    const size_t O_ACTX  = 35266560;                 // 10027008 (A-bf16 / ctx-bf16 / y2 fp32)
    const size_t O_ENCBF = 45293568;                 // 5013504  (39168*256 bf16)
    const size_t O_WBF   = 50307072;                 // 1114112  (2228224 bf16)
    const size_t TOTALF  = 51421184;                 // ~205.7 MB

    if (ws_size < TOTALF * sizeof(float)) {
        fprintf(stderr, "kernel_launch: ws_size %zu < required %zu bytes\n",
                ws_size, TOTALF * sizeof(float));
        return;
    }
    float* ws    = (float*)d_ws;
    float* pe    = ws + O_PE;
    float* whhT  = ws + O_WHHT;
    float* emb   = ws + O_EMB;
    float* encT  = ws + O_ENCT;
    float* encF  = ws + O_ENCF;
    float* scr_f = ws + O_SCR;   u16* scr_b  = (u16*)scr_f;
    float* actx_f= ws + O_ACTX;  u16* actx_b = (u16*)actx_f;
    u16*   encbf = (u16*)(ws + O_ENCBF);
    u16*   wbf   = (u16*)(ws + O_WBF);

    // bf16 weight casts (per encoder: inW 65536 | attnW 524288 | ff1 262144 | ff2 262144)
    const size_t PER_ENC = 1114112;
    struct { const float* src; size_t off; int n; } casts[8] = {
        { t_in_W,   0,               65536  },
        { t_attn_W, 65536,           524288 },
        { t_ff_W1,  589824,          262144 },
        { t_ff_W2,  851968,          262144 },
        { f_in_W,   PER_ENC + 0,     65536  },
        { f_attn_W, PER_ENC + 65536, 524288 },
        { f_ff_W1,  PER_ENC + 589824, 262144 },
        { f_ff_W2,  PER_ENC + 851968, 262144 },
    };
    for (int i = 0; i < 8; i++)
        cast_bf16_kernel<<<(casts[i].n + 255) / 256, 256, 0, stream>>>(casts[i].src, wbf + casts[i].off, casts[i].n);

    WB wbT = { wbf + 0, wbf + 65536, wbf + 589824, wbf + 851968 };
    WB wbF = { wbf + PER_ENC, wbf + PER_ENC + 65536, wbf + PER_ENC + 589824, wbf + PER_ENC + 851968 };

    pe_kernel<<<SEQ_F, 256, 0, stream>>>(pe);
    transpose_whh_kernel<<<768, 256, 0, stream>>>(gru_Whh, whhT);

    grud_kernel<<<BB, 768, 0, stream>>>(x, h0, m, dd, x_m, dec_w, dec_b, hd_W, hd_b,
                                        gru_Wih, gru_bih, whhT, gru_bhh, emb);

    // Text encoder
    gather_kernel<<<BB * SEQ_T, 256, 0, stream>>>(txts, txt_emb, actx_b);
    run_encoder(encT, encbf, actx_b, actx_f, scr_f, scr_b, wbT, pe, SEQ_T,
                t_in_b, t_attn_b, t_ff_b1, t_ff_b2, t_ln_g, t_ln_b, txt_len, 0, stream);

    // Fusion encoder
    build_seq_kernel<<<BB * SEQ_F, 256, 0, stream>>>(emb, encT, f_cls, actx_b);
    run_encoder(encF, encbf, actx_b, actx_f, scr_f, scr_b, wbF, pe, SEQ_F,
                f_in_b, f_attn_b, f_ff_b1, f_ff_b2, f_ln_g, f_ln_b, txt_len, 25, stream);

    classifier_kernel<<<dim3(12, BB), 64, 0, stream>>>(encF, age, gen, fc1_W, fc1_b,
                                                       bn_g, bn_b, fc2_W, fc2_b, outp);
}

// Round 4
// 1004.796 us; speedup vs baseline: 4.3806x; 1.0435x over previous
//
#include <hip/hip_runtime.h>
#include <cstdio>
#include <cstddef>

// Problem dims
#define BB    256
#define TT    24
#define NFEAT 12
#define DIM   256
#define NH    8
#define DKH   32
#define FFD   512
#define SEQ_T 128
#define SEQ_F 153
#define NLAY  2

typedef unsigned short u16;
typedef u16   __attribute__((ext_vector_type(8))) u16x8;
typedef short __attribute__((ext_vector_type(8))) s16x8;
typedef float __attribute__((ext_vector_type(4))) f32x4;

__device__ inline u16 f2bf(float f) {
    union { float f; unsigned u; } v; v.f = f;
    unsigned r = v.u + 0x7FFFu + ((v.u >> 16) & 1u);
    return (u16)(r >> 16);
}
__device__ inline float bf2f(u16 h) {
    union { unsigned u; float f; } v; v.u = ((unsigned)h) << 16;
    return v.f;
}

// async global->LDS, 16B per lane. LDS dest is wave-uniform base + lane*16.
__device__ __forceinline__ void gload16(const u16* g, u16* l) {
    __builtin_amdgcn_global_load_lds(
        (const __attribute__((address_space(1))) unsigned int*)g,
        (__attribute__((address_space(3))) unsigned int*)l, 16, 0, 0);
}

// ---------------------------------------------------------------------------
__global__ void cast_bf16_kernel(const float* __restrict__ in, u16* __restrict__ outp, int n) {
    int i = blockIdx.x * 256 + threadIdx.x;
    int stride = gridDim.x * 256;
    for (; i < n; i += stride) outp[i] = f2bf(in[i]);
}

// PE table
__global__ void pe_kernel(float* __restrict__ pe) {
    int s = blockIdx.x, i = threadIdx.x;
    float e = (float)(2 * (i / 2)) * (1.0f / 256.0f);
    float freq = expf(-e * 9.210340371976184f);
    float ang = (float)s * freq;
    pe[s * 256 + i] = (i & 1) ? cosf(ang) : sinf(ang);
}

// Transpose gru_Whh (768x256) -> (256x768)
__global__ void transpose_whh_kernel(const float* __restrict__ Whh, float* __restrict__ Wt) {
    int n = blockIdx.x, k = threadIdx.x;
    Wt[(size_t)k * 768 + n] = Whh[(size_t)n * 256 + k];
}

// ---------------------------------------------------------------------------
// GRU-D scan: one block (768 threads = one per gate-output) per batch element.
__global__ __launch_bounds__(768) void grud_kernel(
    const float* __restrict__ x, const float* __restrict__ h0,
    const float* __restrict__ m, const float* __restrict__ dd,
    const float* __restrict__ x_m,
    const float* __restrict__ dec_w, const float* __restrict__ dec_b,
    const float* __restrict__ hd_W, const float* __restrict__ hd_b,
    const float* __restrict__ Wih, const float* __restrict__ bih,
    const float* __restrict__ WhhT, const float* __restrict__ bhh,
    float* __restrict__ emb)
{
    int b = blockIdx.x;
    int tid = threadIdx.x;          // 0..767
    int gate = tid >> 8;            // 0=r 1=z 2=n
    int j = tid & 255;
    __shared__ float hcs[256], hdecs[256], r_s[256], z_s[256];
    __shared__ float dts[12], xcm[24];

    float wih[24];
#pragma unroll
    for (int i = 0; i < 24; i++) wih[i] = Wih[(size_t)tid * 24 + i];
    float bi = bih[tid], bh = bhh[tid];

    float hdw[12]; float hdb = 0.0f;
    if (tid < 256) {
#pragma unroll
        for (int i = 0; i < 12; i++) hdw[i] = hd_W[tid * 12 + i];
        hdb = hd_b[tid];
        hcs[tid] = h0[(size_t)b * 256 + tid];
    }
    __syncthreads();

    for (int t = 0; t < TT; t++) {
        if (tid < 12) {
            size_t idx = ((size_t)b * TT + t) * NFEAT + tid;
            float dv = dd[idx], xv = x[idx], mv = m[idx];
            float xd = expf(-fmaxf(dv * dec_w[tid] + dec_b[tid], 0.0f));
            dts[tid] = dv;
            xcm[tid] = mv * xv + (1.0f - mv) * xd * xv + (1.0f - mv) * (1.0f - xd) * x_m[tid];
            xcm[12 + tid] = mv;
        }
        __syncthreads();
        if (tid < 256) {
            float acc = hdb;
#pragma unroll
            for (int i = 0; i < 12; i++) acc += hdw[i] * dts[i];
            hdecs[tid] = expf(-fmaxf(acc, 0.0f)) * hcs[tid];
        }
        __syncthreads();
        float acc_i = bi;
#pragma unroll
        for (int i = 0; i < 24; i++) acc_i += wih[i] * xcm[i];
        float acc_h = bh;
#pragma unroll 8
        for (int k = 0; k < 256; k++) acc_h += WhhT[(size_t)k * 768 + tid] * hdecs[k];
        if (gate == 0) r_s[j] = 1.0f / (1.0f + expf(-(acc_i + acc_h)));
        else if (gate == 1) z_s[j] = 1.0f / (1.0f + expf(-(acc_i + acc_h)));
        __syncthreads();
        if (gate == 2) {
            float n = tanhf(acc_i + r_s[j] * acc_h);
            float hnew = (1.0f - z_s[j]) * n + z_s[j] * hdecs[j];
            hcs[j] = hnew;
            emb[((size_t)b * TT + t) * 256 + j] = hnew;
        }
        __syncthreads();
    }
}

// ---------------------------------------------------------------------------
// Embedding gather -> bf16
__global__ void gather_kernel(const int* __restrict__ txts, const float* __restrict__ txt_emb,
                              u16* __restrict__ outp) {
    int r = blockIdx.x, i = threadIdx.x;
    outp[(size_t)r * 256 + i] = f2bf(txt_emb[(size_t)txts[r] * 256 + i]);
}

// Build fusion sequence -> bf16: [cls, emb(24), encT(128)]
__global__ void build_seq_kernel(const float* __restrict__ emb, const float* __restrict__ encT,
                                 const float* __restrict__ fcls, u16* __restrict__ seq) {
    int r = blockIdx.x, i = threadIdx.x;
    int b = r / SEQ_F, s = r - b * SEQ_F;
    float v;
    if (s == 0)       v = fcls[i];
    else if (s < 25)  v = emb[((size_t)b * TT + (s - 1)) * 256 + i];
    else              v = encT[((size_t)b * SEQ_T + (s - 25)) * 256 + i];
    seq[(size_t)r * 256 + i] = f2bf(v);
}

// ---------------------------------------------------------------------------
// bf16 MFMA GEMM, m97-structure: 128x128 tile, BK=32, linear LDS [128][32],
// staging via global_load_lds width=16. 4 waves, each 64x64 output.
template <int OUT_BF16, int RELU>
__global__ __launch_bounds__(256) void gemm_bf16_kernel(
    const u16* __restrict__ A, const u16* __restrict__ W,
    const float* __restrict__ bias, void* __restrict__ Cout,
    int M, int N, int K)
{
    __shared__ u16 As[128 * 32];
    __shared__ u16 Bs[128 * 32];
    const int bm = blockIdx.y * 128, bn = blockIdx.x * 128;
    const int tid = threadIdx.x;
    const int w = tid >> 6, lane = tid & 63;
    const int wm = (w >> 1) * 64, wn = (w & 1) * 64;
    const int l15 = lane & 15, l16 = lane >> 4;
    // staging source: wave w covers rows [32w,32w+32); lane l -> row 32w+(l>>2), col (l&3)*8
    const int srow = 32 * w + (lane >> 2);
    const int scol = (lane & 3) * 8;
    f32x4 acc[4][4] = {};

    for (int k0 = 0; k0 < K; k0 += 32) {
        __syncthreads();  // all waves done reading previous tile
        const u16* ga = A + (size_t)(bm + srow) * K + k0 + scol;
        const u16* gb = W + (size_t)(bn + srow) * K + k0 + scol;
        gload16(ga,          &As[w * 1024]);
        gload16(ga + 16 * K, &As[w * 1024 + 512]);
        gload16(gb,          &Bs[w * 1024]);
        gload16(gb + 16 * K, &Bs[w * 1024 + 512]);
        __syncthreads();  // drains vmcnt -> LDS tiles ready
        s16x8 af[4], bfr[4];
#pragma unroll
        for (int i = 0; i < 4; i++)
            af[i] = *(const s16x8*)&As[(wm + i * 16 + l15) * 32 + l16 * 8];
#pragma unroll
        for (int i = 0; i < 4; i++)
            bfr[i] = *(const s16x8*)&Bs[(wn + i * 16 + l15) * 32 + l16 * 8];
#pragma unroll
        for (int mi = 0; mi < 4; mi++)
#pragma unroll
            for (int ni = 0; ni < 4; ni++)
                acc[mi][ni] = __builtin_amdgcn_mfma_f32_16x16x32_bf16(af[mi], bfr[ni], acc[mi][ni], 0, 0, 0);
    }
#pragma unroll
    for (int mi = 0; mi < 4; mi++)
#pragma unroll
        for (int ni = 0; ni < 4; ni++) {
            int col = bn + wn + ni * 16 + l15;
            float bv = bias[col];
#pragma unroll
            for (int r = 0; r < 4; r++) {
                int row = bm + wm + mi * 16 + l16 * 4 + r;
                float v = acc[mi][ni][r] + bv;
                if (RELU) v = fmaxf(v, 0.0f);
                if (OUT_BF16) ((u16*)Cout)[(size_t)row * N + col] = f2bf(v);
                else          ((float*)Cout)[(size_t)row * N + col] = v;
            }
        }
}

// ---------------------------------------------------------------------------
// LayerNorm(row)*g+b + PE[s]  -> enc fp32 + enc bf16
__global__ __launch_bounds__(64) void ln_pe_kernel(
    const float* __restrict__ y, const float* __restrict__ g, const float* __restrict__ b,
    const float* __restrict__ pe, float* __restrict__ outp, u16* __restrict__ outb, int S)
{
    int r = blockIdx.x, t = threadIdx.x;
    const float* yr = y + (size_t)r * 256;
    float v[4]; float s = 0.0f;
#pragma unroll
    for (int i = 0; i < 4; i++) { v[i] = yr[t + 64 * i]; s += v[i]; }
#pragma unroll
    for (int o = 32; o >= 1; o >>= 1) s += __shfl_xor(s, o, 64);
    float mean = s * (1.0f / 256.0f);
    float vs = 0.0f;
#pragma unroll
    for (int i = 0; i < 4; i++) { float dlt = v[i] - mean; vs += dlt * dlt; }
#pragma unroll
    for (int o = 32; o >= 1; o >>= 1) vs += __shfl_xor(vs, o, 64);
    float rstd = rsqrtf(vs * (1.0f / 256.0f) + 1e-5f);
    int srow = r % S;
#pragma unroll
    for (int i = 0; i < 4; i++) {
        int c = t + 64 * i;
        float o = (v[i] - mean) * rstd * g[c] + b[c] + pe[srow * 256 + c];
        outp[(size_t)r * 256 + c] = o;
        outb[(size_t)r * 256 + c] = f2bf(o);
    }
}

// LayerNorm(y+res)*g+b * npad -> enc fp32 + bf16 (out may alias res)
__global__ __launch_bounds__(64) void add_ln_mask_kernel(
    const float* __restrict__ y, const float* __restrict__ res,
    const float* __restrict__ g, const float* __restrict__ b,
    const int* __restrict__ lengths, int len_add, int S,
    float* __restrict__ outp, u16* __restrict__ outb)
{
    int r = blockIdx.x, t = threadIdx.x;
    int bb = r / S, srow = r - bb * S;
    float mask = (srow < lengths[bb] + len_add) ? 1.0f : 0.0f;
    float v[4]; float s = 0.0f;
#pragma unroll
    for (int i = 0; i < 4; i++) {
        v[i] = y[(size_t)r * 256 + t + 64 * i] + res[(size_t)r * 256 + t + 64 * i];
        s += v[i];
    }
#pragma unroll
    for (int o = 32; o >= 1; o >>= 1) s += __shfl_xor(s, o, 64);
    float mean = s * (1.0f / 256.0f);
    float vs = 0.0f;
#pragma unroll
    for (int i = 0; i < 4; i++) { float dlt = v[i] - mean; vs += dlt * dlt; }
#pragma unroll
    for (int o = 32; o >= 1; o >>= 1) vs += __shfl_xor(vs, o, 64);
    float rstd = rsqrtf(vs * (1.0f / 256.0f) + 1e-5f);
#pragma unroll
    for (int i = 0; i < 4; i++) {
        int c = t + 64 * i;
        float o = ((v[i] - mean) * rstd * g[c] + b[c]) * mask;
        outp[(size_t)r * 256 + c] = o;
        outb[(size_t)r * 256 + c] = f2bf(o);
    }
}

// ---------------------------------------------------------------------------
// MFMA flash attention. One block per (b,h), 256 threads (4 waves).
// K/V staged ONCE; each wave loops q-tiles (16 rows) at stride 64.
// S^T = mfma(K, Q); PV as O^T = mfma(V^T, P^T) with P routed via per-wave LDS.
__global__ __launch_bounds__(256) void attn_mfma_kernel(
    const u16* __restrict__ qkv, u16* __restrict__ ctx,
    const int* __restrict__ lengths, int len_add, int S)
{
    __shared__ u16 K_lds[160][40];    // [key][d]
    __shared__ u16 Vt_lds[32][176];   // [d][key], 16B-aligned rows
    __shared__ u16 P_lds[4][16][48];  // per-wave [q][key-local], 16B-aligned rows

    const int bh = blockIdx.x;
    const int b = bh >> 3, h = bh & 7;
    const int len = lengths[b] + len_add;
    const int tid = threadIdx.x;
    const int w = tid >> 6;
    const int lane = tid & 63;
    const int l15 = lane & 15, l16 = lane >> 4;

    // Stage K row-major and V transposed; zero-fill rows [S,160) (NaN safety).
    const u16* kbase = qkv + ((size_t)b * S) * 768 + 256 + h * 32;
    const u16* vbase = kbase + 256;
    for (int chunk = tid; chunk < 160 * 4; chunk += 256) {
        int s = chunk >> 2, d8 = (chunk & 3) * 8;
        u16x8 kv = {}; u16x8 vv = {};
        if (s < S) {
            kv = *(const u16x8*)(kbase + (size_t)s * 768 + d8);
            vv = *(const u16x8*)(vbase + (size_t)s * 768 + d8);
        }
        *(u16x8*)&K_lds[s][d8] = kv;
#pragma unroll
        for (int j = 0; j < 8; j++) Vt_lds[d8 + j][s] = vv[j];
    }
    __syncthreads();

    const f32x4 zero4 = {0.0f, 0.0f, 0.0f, 0.0f};
    const float SCALE = 0.17677669529663687f;

    for (int q0 = w * 16; q0 < S; q0 += 64) {
        const int qr = min(q0 + l15, S - 1);
        s16x8 qf = *(const s16x8*)(qkv + ((size_t)(b * S + qr)) * 768 + h * 32 + l16 * 8);
        f32x4 o0 = zero4, o1 = zero4;
        float mreg = -1e30f, lreg = 0.0f;

        for (int k0 = 0; k0 < len; k0 += 32) {
            s16x8 kf0 = *(const s16x8*)&K_lds[k0 + l15][l16 * 8];
            s16x8 kf1 = *(const s16x8*)&K_lds[k0 + 16 + l15][l16 * 8];
            f32x4 c0 = __builtin_amdgcn_mfma_f32_16x16x32_bf16(kf0, qf, zero4, 0, 0, 0);
            f32x4 c1 = __builtin_amdgcn_mfma_f32_16x16x32_bf16(kf1, qf, zero4, 0, 0, 0);
            float sc[8];
#pragma unroll
            for (int r = 0; r < 4; r++) {
                int key0 = k0 + l16 * 4 + r;
                sc[r]     = (key0 < len)      ? c0[r] * SCALE : -1e30f;
                sc[4 + r] = (key0 + 16 < len) ? c1[r] * SCALE : -1e30f;
            }
            float tmax = sc[0];
#pragma unroll
            for (int i = 1; i < 8; i++) tmax = fmaxf(tmax, sc[i]);
            tmax = fmaxf(tmax, __shfl_xor(tmax, 16, 64));
            tmax = fmaxf(tmax, __shfl_xor(tmax, 32, 64));
            float mnew = fmaxf(mreg, tmax);
            float rescale = expf(mreg - mnew);
            float psum = 0.0f;
            u16 pb[8];
#pragma unroll
            for (int i = 0; i < 8; i++) {
                float p = expf(sc[i] - mnew);
                psum += p;
                pb[i] = f2bf(p);
            }
            psum += __shfl_xor(psum, 16, 64);
            psum += __shfl_xor(psum, 32, 64);
            lreg = lreg * rescale + psum;
            mreg = mnew;
#pragma unroll
            for (int i = 0; i < 4; i++) { o0[i] *= rescale; o1[i] *= rescale; }
#pragma unroll
            for (int r = 0; r < 4; r++) {
                P_lds[w][l15][l16 * 4 + r]      = pb[r];
                P_lds[w][l15][16 + l16 * 4 + r] = pb[4 + r];
            }
            s16x8 pf  = *(const s16x8*)&P_lds[w][l15][l16 * 8];
            s16x8 vf0 = *(const s16x8*)&Vt_lds[l15][k0 + l16 * 8];
            s16x8 vf1 = *(const s16x8*)&Vt_lds[16 + l15][k0 + l16 * 8];
            o0 = __builtin_amdgcn_mfma_f32_16x16x32_bf16(vf0, pf, o0, 0, 0, 0);
            o1 = __builtin_amdgcn_mfma_f32_16x16x32_bf16(vf1, pf, o1, 0, 0, 0);
        }

        float inv = 1.0f / lreg;
        int qg = q0 + l15;
        if (qg < S) {
            size_t ob = ((size_t)(b * S + qg)) * 256 + h * 32;
#pragma unroll
            for (int r = 0; r < 4; r++) {
                ctx[ob + l16 * 4 + r]      = f2bf(o0[r] * inv);
                ctx[ob + 16 + l16 * 4 + r] = f2bf(o1[r] * inv);
            }
        }
    }
}

// ---------------------------------------------------------------------------
__global__ __launch_bounds__(64) void classifier_kernel(
    const float* __restrict__ encF, const float* __restrict__ age, const float* __restrict__ gen,
    const float* __restrict__ fc1_W, const float* __restrict__ fc1_b,
    const float* __restrict__ bn_g, const float* __restrict__ bn_b,
    const float* __restrict__ fc2_W, const float* __restrict__ fc2_b,
    float* __restrict__ outp)
{
    int k = blockIdx.x, b = blockIdx.y, t = threadIdx.x;
    const float* cls = encF + (size_t)b * SEQ_F * 256;
    const float* wrow = fc1_W + ((size_t)k * 64 + t) * 258;
    float acc = fc1_b[k * 64 + t];
    for (int d2 = 0; d2 < 256; d2++) acc += cls[d2] * wrow[d2];
    acc += age[b] * wrow[256] + gen[b] * wrow[257];
    const float RSQ = 0.99999500003749980e0f;
    acc = acc * RSQ * bn_g[k * 64 + t] + bn_b[k * 64 + t];
    acc = fmaxf(acc, 0.0f);
    float p = acc * fc2_W[k * 64 + t];
#pragma unroll
    for (int o = 32; o >= 1; o >>= 1) p += __shfl_xor(p, o, 64);
    if (t == 0) outp[k * 256 + b] = 1.0f / (1.0f + expf(-(p + fc2_b[k])));
}

// ---------------------------------------------------------------------------
struct WB { const u16 *inW, *attnW, *ff1W, *ff2W; };

static void run_encoder(float* enc, u16* enc_bf,
                        u16* actx_b, float* actx_f,
                        float* scr_f, u16* scr_b,
                        const WB& wb, const float* pe, int S,
                        const float* in_b, const float* attn_b,
                        const float* ff_b1, const float* ff_b2,
                        const float* ln_g, const float* ln_b,
                        const int* lengths, int len_add, hipStream_t stream)
{
    int M = BB * S;
    dim3 g256(256 / 128, M / 128), g512(512 / 128, M / 128), g768(768 / 128, M / 128);
    // input projection (A = actx_b bf16) -> scr_f fp32; LN+PE -> enc, enc_bf
    gemm_bf16_kernel<0, 0><<<g256, 256, 0, stream>>>(actx_b, wb.inW, in_b, scr_f, M, 256, 256);
    ln_pe_kernel<<<M, 64, 0, stream>>>(scr_f, ln_g, ln_b, pe, enc, enc_bf, S);
    for (int l = 0; l < NLAY; l++) {
        const u16* wqkv = wb.attnW + (size_t)l * 4 * 65536;
        const u16* wout = wb.attnW + ((size_t)l * 4 + 3) * 65536;
        const float* bqkv = attn_b + (size_t)l * 4 * 256;
        const float* bout = attn_b + ((size_t)l * 4 + 3) * 256;
        // qkv (bf16 out) -> scr_b
        gemm_bf16_kernel<1, 0><<<g768, 256, 0, stream>>>(enc_bf, wqkv, bqkv, scr_b, M, 768, 256);
        // attention -> ctx (bf16, actx_b)
        attn_mfma_kernel<<<BB * NH, 256, 0, stream>>>(scr_b, actx_b, lengths, len_add, S);
        // out proj -> scr_f fp32
        gemm_bf16_kernel<0, 0><<<g256, 256, 0, stream>>>(actx_b, wout, bout, scr_f, M, 256, 256);
        add_ln_mask_kernel<<<M, 64, 0, stream>>>(scr_f, enc, ln_g + (1 + 2 * l) * 256, ln_b + (1 + 2 * l) * 256,
                                                 lengths, len_add, S, enc, enc_bf);
        // ff1 (relu, bf16 out) -> scr_b
        gemm_bf16_kernel<1, 1><<<g512, 256, 0, stream>>>(enc_bf, wb.ff1W + (size_t)l * 512 * 256,
                                                         ff_b1 + l * 512, scr_b, M, 512, 256);
        // ff2 -> actx_f fp32
        gemm_bf16_kernel<0, 0><<<g256, 256, 0, stream>>>(scr_b, wb.ff2W + (size_t)l * 256 * 512,
                                                         ff_b2 + l * 256, actx_f, M, 256, 512);
        add_ln_mask_kernel<<<M, 64, 0, stream>>>(actx_f, enc, ln_g + (2 + 2 * l) * 256, ln_b + (2 + 2 * l) * 256,
                                                 lengths, len_add, S, enc, enc_bf);
    }
}

// ---------------------------------------------------------------------------
extern "C" void kernel_launch(void* const* d_in, const int* in_sizes, int n_in,
                              void* d_out, int out_size, void* d_ws, size_t ws_size,
                              hipStream_t stream)
{
    const float* x        = (const float*)d_in[0];
    const float* h0       = (const float*)d_in[1];
    const float* m        = (const float*)d_in[2];
    const float* dd       = (const float*)d_in[3];
    const float* x_m      = (const float*)d_in[4];
    const float* age      = (const float*)d_in[5];
    const float* gen      = (const float*)d_in[6];
    const int*   txts     = (const int*)d_in[8];
    const int*   txt_len  = (const int*)d_in[9];
    const float* dec_w    = (const float*)d_in[10];
    const float* dec_b    = (const float*)d_in[11];
    const float* hd_W     = (const float*)d_in[12];
    const float* hd_b     = (const float*)d_in[13];
    const float* gru_Wih  = (const float*)d_in[14];
    const float* gru_Whh  = (const float*)d_in[15];
    const float* gru_bih  = (const float*)d_in[16];
    const float* gru_bhh  = (const float*)d_in[17];
    const float* txt_emb  = (const float*)d_in[18];
    const float* t_in_W   = (const float*)d_in[19];
    const float* t_in_b   = (const float*)d_in[20];
    const float* t_attn_W = (const float*)d_in[21];
    const float* t_attn_b = (const float*)d_in[22];
    const float* t_ff_W1  = (const float*)d_in[23];
    const float* t_ff_b1  = (const float*)d_in[24];
    const float* t_ff_W2  = (const float*)d_in[25];
    const float* t_ff_b2  = (const float*)d_in[26];
    const float* t_ln_g   = (const float*)d_in[27];
    const float* t_ln_b   = (const float*)d_in[28];
    const float* f_in_W   = (const float*)d_in[29];
    const float* f_in_b   = (const float*)d_in[30];
    const float* f_attn_W = (const float*)d_in[31];
    const float* f_attn_b = (const float*)d_in[32];
    const float* f_ff_W1  = (const float*)d_in[33];
    const float* f_ff_b1  = (const float*)d_in[34];
    const float* f_ff_W2  = (const float*)d_in[35];
    const float* f_ff_b2  = (const float*)d_in[36];
    const float* f_ln_g   = (const float*)d_in[37];
    const float* f_ln_b   = (const float*)d_in[38];
    const float* f_cls    = (const float*)d_in[39];
    const float* fc1_W    = (const float*)d_in[40];
    const float* fc1_b    = (const float*)d_in[41];
    const float* bn_g     = (const float*)d_in[42];
    const float* bn_b     = (const float*)d_in[43];
    const float* fc2_W    = (const float*)d_in[44];
    const float* fc2_b    = (const float*)d_in[45];
    float* outp = (float*)d_out;

    // Workspace layout (float units)
    const size_t O_PE    = 0;                        // 40960
    const size_t O_WHHT  = 40960;                    // 196608
    const size_t O_EMB   = 237568;                   // 1572864
    const size_t O_ENCT  = 1810432;                  // 8388608
    const size_t O_ENCF  = 10199040;                 // 10027008
    const size_t O_SCR   = 20226048;                 // 15040512 (qkv bf16 / y fp32 / ff1 bf16)
    const size_t O_ACTX  = 35266560;                 // 10027008 (A-bf16 / ctx-bf16 / y2 fp32)
    const size_t O_ENCBF = 45293568;                 // 5013504  (39168*256 bf16)
    const size_t O_WBF   = 50307072;                 // 1114112  (2228224 bf16)
    const size_t TOTALF  = 51421184;                 // ~205.7 MB

    if (ws_size < TOTALF * sizeof(float)) {
        fprintf(stderr, "kernel_launch: ws_size %zu < required %zu bytes\n",
                ws_size, TOTALF * sizeof(float));
        return;
    }
    float* ws    = (float*)d_ws;
    float* pe    = ws + O_PE;
    float* whhT  = ws + O_WHHT;
    float* emb   = ws + O_EMB;
    float* encT  = ws + O_ENCT;
    float* encF  = ws + O_ENCF;
    float* scr_f = ws + O_SCR;   u16* scr_b  = (u16*)scr_f;
    float* actx_f= ws + O_ACTX;  u16* actx_b = (u16*)actx_f;
    u16*   encbf = (u16*)(ws + O_ENCBF);
    u16*   wbf   = (u16*)(ws + O_WBF);

    // bf16 weight casts (per encoder: inW 65536 | attnW 524288 | ff1 262144 | ff2 262144)
    const size_t PER_ENC = 1114112;
    struct { const float* src; size_t off; int n; } casts[8] = {
        { t_in_W,   0,               65536  },
        { t_attn_W, 65536,           524288 },
        { t_ff_W1,  589824,          262144 },
        { t_ff_W2,  851968,          262144 },
        { f_in_W,   PER_ENC + 0,     65536  },
        { f_attn_W, PER_ENC + 65536, 524288 },
        { f_ff_W1,  PER_ENC + 589824, 262144 },
        { f_ff_W2,  PER_ENC + 851968, 262144 },
    };
    for (int i = 0; i < 8; i++)
        cast_bf16_kernel<<<(casts[i].n + 255) / 256, 256, 0, stream>>>(casts[i].src, wbf + casts[i].off, casts[i].n);

    WB wbT = { wbf + 0, wbf + 65536, wbf + 589824, wbf + 851968 };
    WB wbF = { wbf + PER_ENC, wbf + PER_ENC + 65536, wbf + PER_ENC + 589824, wbf + PER_ENC + 851968 };

    pe_kernel<<<SEQ_F, 256, 0, stream>>>(pe);
    transpose_whh_kernel<<<768, 256, 0, stream>>>(gru_Whh, whhT);

    grud_kernel<<<BB, 768, 0, stream>>>(x, h0, m, dd, x_m, dec_w, dec_b, hd_W, hd_b,
                                        gru_Wih, gru_bih, whhT, gru_bhh, emb);

    // Text encoder
    gather_kernel<<<BB * SEQ_T, 256, 0, stream>>>(txts, txt_emb, actx_b);
    run_encoder(encT, encbf, actx_b, actx_f, scr_f, scr_b, wbT, pe, SEQ_T,
                t_in_b, t_attn_b, t_ff_b1, t_ff_b2, t_ln_g, t_ln_b, txt_len, 0, stream);

    // Fusion encoder
    build_seq_kernel<<<BB * SEQ_F, 256, 0, stream>>>(emb, encT, f_cls, actx_b);
    run_encoder(encF, encbf, actx_b, actx_f, scr_f, scr_b, wbF, pe, SEQ_F,
                f_in_b, f_attn_b, f_ff_b1, f_ff_b2, f_ln_g, f_ln_b, txt_len, 25, stream);

    classifier_kernel<<<dim3(12, BB), 64, 0, stream>>>(encF, age, gen, fc1_W, fc1_b,
                                                       bn_g, bn_b, fc2_W, fc2_b, outp);
}